// Round 1
// baseline (6916.319 us; speedup 1.0000x reference)
//
#include <hip/hip_runtime.h>
#include <hip/hip_bf16.h>

#define KDIM 128

// ---------------------------------------------------------------------------
// GEMM: C[M,NOUT] = act(A[M,128]) @ W[128,NOUT], act = ReLU if RELU.
// Block: 256 threads, BM=32 rows. W staged in two 64-row LDS slabs; A tile
// staged transposed in LDS so the k-loop reads row-pairs as float2.
// Per thread: 2 rows x CPT cols register tile.
// ---------------------------------------------------------------------------
template<int NOUT, bool RELU>
__global__ __launch_bounds__(256) void gemm_k(const float* __restrict__ A,
                                              const float* __restrict__ W,
                                              float* __restrict__ C, int M) {
  constexpr int BM = 32;
  constexpr int CPT = NOUT / 16;          // 8 for NOUT=128, 4 for NOUT=64
  __shared__ float Ws[64][NOUT];          // half-K slab of W
  __shared__ float At[KDIM][BM + 2];      // A tile, transposed, padded
  const int tid = threadIdx.x;
  const int row0 = blockIdx.x * BM;

  // Stage A tile (transposed), fusing ReLU of the previous layer on load.
  for (int i = tid; i < BM * (KDIM / 4); i += 256) {
    const int r = i / (KDIM / 4);
    const int c4 = i % (KDIM / 4);
    const int gr = row0 + r;
    float4 v = make_float4(0.f, 0.f, 0.f, 0.f);
    if (gr < M) v = *reinterpret_cast<const float4*>(&A[(size_t)gr * KDIM + c4 * 4]);
    if (RELU) {
      v.x = fmaxf(v.x, 0.f); v.y = fmaxf(v.y, 0.f);
      v.z = fmaxf(v.z, 0.f); v.w = fmaxf(v.w, 0.f);
    }
    At[c4 * 4 + 0][r] = v.x;
    At[c4 * 4 + 1][r] = v.y;
    At[c4 * 4 + 2][r] = v.z;
    At[c4 * 4 + 3][r] = v.w;
  }

  const int rg = tid & 15;                // row pair: rows rg*2, rg*2+1
  const int cg = tid >> 4;                // col group: cols cg*CPT ..
  float4 acc0a = make_float4(0.f, 0.f, 0.f, 0.f);
  float4 acc1a = make_float4(0.f, 0.f, 0.f, 0.f);
  float4 acc0b = make_float4(0.f, 0.f, 0.f, 0.f);
  float4 acc1b = make_float4(0.f, 0.f, 0.f, 0.f);

  for (int kt = 0; kt < 2; ++kt) {
    __syncthreads();                      // At ready (kt=0) / Ws free (kt=1)
    for (int i = tid * 4; i < 64 * NOUT; i += 1024) {
      *reinterpret_cast<float4*>(&Ws[0][0] + i) =
          *reinterpret_cast<const float4*>(&W[(size_t)kt * 64 * NOUT + i]);
    }
    __syncthreads();
    #pragma unroll 8
    for (int kk = 0; kk < 64; ++kk) {
      const int k = kt * 64 + kk;
      const float2 a = *reinterpret_cast<const float2*>(&At[k][rg * 2]);
      const float4 w0 = *reinterpret_cast<const float4*>(&Ws[kk][cg * CPT]);
      acc0a.x = fmaf(a.x, w0.x, acc0a.x);
      acc0a.y = fmaf(a.x, w0.y, acc0a.y);
      acc0a.z = fmaf(a.x, w0.z, acc0a.z);
      acc0a.w = fmaf(a.x, w0.w, acc0a.w);
      acc1a.x = fmaf(a.y, w0.x, acc1a.x);
      acc1a.y = fmaf(a.y, w0.y, acc1a.y);
      acc1a.z = fmaf(a.y, w0.z, acc1a.z);
      acc1a.w = fmaf(a.y, w0.w, acc1a.w);
      if constexpr (CPT == 8) {
        const float4 w1 = *reinterpret_cast<const float4*>(&Ws[kk][cg * CPT + 4]);
        acc0b.x = fmaf(a.x, w1.x, acc0b.x);
        acc0b.y = fmaf(a.x, w1.y, acc0b.y);
        acc0b.z = fmaf(a.x, w1.z, acc0b.z);
        acc0b.w = fmaf(a.x, w1.w, acc0b.w);
        acc1b.x = fmaf(a.y, w1.x, acc1b.x);
        acc1b.y = fmaf(a.y, w1.y, acc1b.y);
        acc1b.z = fmaf(a.y, w1.z, acc1b.z);
        acc1b.w = fmaf(a.y, w1.w, acc1b.w);
      }
    }
  }

  const int gr0 = row0 + rg * 2;
  if (gr0 < M) {
    *reinterpret_cast<float4*>(&C[(size_t)gr0 * NOUT + cg * CPT]) = acc0a;
    if constexpr (CPT == 8)
      *reinterpret_cast<float4*>(&C[(size_t)gr0 * NOUT + cg * CPT + 4]) = acc0b;
  }
  if (gr0 + 1 < M) {
    *reinterpret_cast<float4*>(&C[(size_t)(gr0 + 1) * NOUT + cg * CPT]) = acc1a;
    if constexpr (CPT == 8)
      *reinterpret_cast<float4*>(&C[(size_t)(gr0 + 1) * NOUT + cg * CPT + 4]) = acc1b;
  }
}

// ---------------------------------------------------------------------------
// Scatter-add: AGG[dst[e], :] += H[src[e], :]. One thread per (edge, float4).
// ---------------------------------------------------------------------------
template<int D>
__global__ __launch_bounds__(256) void scatter_k(const float* __restrict__ H,
                                                 const int* __restrict__ src,
                                                 const int* __restrict__ dst,
                                                 float* __restrict__ AGG, int E) {
  constexpr int TPE = D / 4;              // threads per edge
  const unsigned t = blockIdx.x * 256u + threadIdx.x;
  const unsigned e = t / TPE;
  const int c = (int)(t % TPE) * 4;
  if (e >= (unsigned)E) return;
  const int s = src[e];
  const int d = dst[e];
  const float4 v = *reinterpret_cast<const float4*>(&H[(size_t)s * D + c]);
  float* p = &AGG[(size_t)d * D + c];
  atomicAdd(p + 0, v.x);
  atomicAdd(p + 1, v.y);
  atomicAdd(p + 2, v.z);
  atomicAdd(p + 3, v.w);
}

// ---------------------------------------------------------------------------
// Row-wise log_softmax over 64 cols; one wave (64 lanes) per row.
// ---------------------------------------------------------------------------
__global__ __launch_bounds__(256) void logsoftmax_k(const float* __restrict__ X,
                                                    float* __restrict__ out, int M) {
  const int gtid = blockIdx.x * 256 + threadIdx.x;
  const int row = gtid >> 6;
  const int lane = gtid & 63;
  if (row >= M) return;
  const float v = X[(size_t)row * 64 + lane];
  float m = v;
  #pragma unroll
  for (int o = 32; o > 0; o >>= 1) m = fmaxf(m, __shfl_xor(m, o, 64));
  const float ex = __expf(v - m);
  float s = ex;
  #pragma unroll
  for (int o = 32; o > 0; o >>= 1) s += __shfl_xor(s, o, 64);
  out[(size_t)row * 64 + lane] = v - m - __logf(s);
}

extern "C" void kernel_launch(void* const* d_in, const int* in_sizes, int n_in,
                              void* d_out, int out_size, void* d_ws, size_t ws_size,
                              hipStream_t stream) {
  const float* x  = (const float*)d_in[0];
  const int*   ei = (const int*)d_in[1];
  const float* W1 = (const float*)d_in[2];
  const float* W2 = (const float*)d_in[3];
  const float* W3 = (const float*)d_in[4];
  float* out = (float*)d_out;

  const int N = in_sizes[0] / KDIM;       // 100000
  const int E = in_sizes[1] / 2;          // 1600000
  const int* src = ei;
  const int* dst = ei + E;

  float* H   = (float*)d_ws;              // [N,128] transformed features
  float* AGG = H + (size_t)N * KDIM;      // [N,128] aggregation accumulator

  const int gemm_grid = (N + 31) / 32;

  // ---- layer 1: AGG = scatter(x @ W1) ----
  gemm_k<128, false><<<gemm_grid, 256, 0, stream>>>(x, W1, H, N);
  hipMemsetAsync(AGG, 0, (size_t)N * 128 * sizeof(float), stream);
  scatter_k<128><<<((unsigned)E * 32u + 255) / 256, 256, 0, stream>>>(H, src, dst, AGG, E);

  // ---- layer 2: AGG = scatter(relu(AGG) @ W2) ----
  gemm_k<128, true><<<gemm_grid, 256, 0, stream>>>(AGG, W2, H, N);
  hipMemsetAsync(AGG, 0, (size_t)N * 128 * sizeof(float), stream);
  scatter_k<128><<<((unsigned)E * 32u + 255) / 256, 256, 0, stream>>>(H, src, dst, AGG, E);

  // ---- layer 3: AGG = scatter(relu(AGG) @ W3), then log_softmax ----
  gemm_k<64, true><<<gemm_grid, 256, 0, stream>>>(AGG, W3, H, N);
  hipMemsetAsync(AGG, 0, (size_t)N * 64 * sizeof(float), stream);
  scatter_k<64><<<((unsigned)E * 16u + 255) / 256, 256, 0, stream>>>(H, src, dst, AGG, E);

  logsoftmax_k<<<(N * 64 + 255) / 256, 256, 0, stream>>>(AGG, out, N);
}

// Round 2
// 689.788 us; speedup vs baseline: 10.0267x; 10.0267x over previous
//
#include <hip/hip_runtime.h>
#include <hip/hip_bf16.h>

#define KDIM 128

// ---------------------------------------------------------------------------
// GEMM: C[M,NOUT] = act(A[M,128]) @ W[128,NOUT], act = ReLU if RELU.
// ---------------------------------------------------------------------------
template<int NOUT, bool RELU>
__global__ __launch_bounds__(256) void gemm_k(const float* __restrict__ A,
                                              const float* __restrict__ W,
                                              float* __restrict__ C, int M) {
  constexpr int BM = 32;
  constexpr int CPT = NOUT / 16;          // 8 for NOUT=128, 4 for NOUT=64
  __shared__ float Ws[64][NOUT];          // half-K slab of W
  __shared__ float At[KDIM][BM + 2];      // A tile, transposed, padded
  const int tid = threadIdx.x;
  const int row0 = blockIdx.x * BM;

  for (int i = tid; i < BM * (KDIM / 4); i += 256) {
    const int r = i / (KDIM / 4);
    const int c4 = i % (KDIM / 4);
    const int gr = row0 + r;
    float4 v = make_float4(0.f, 0.f, 0.f, 0.f);
    if (gr < M) v = *reinterpret_cast<const float4*>(&A[(size_t)gr * KDIM + c4 * 4]);
    if (RELU) {
      v.x = fmaxf(v.x, 0.f); v.y = fmaxf(v.y, 0.f);
      v.z = fmaxf(v.z, 0.f); v.w = fmaxf(v.w, 0.f);
    }
    At[c4 * 4 + 0][r] = v.x;
    At[c4 * 4 + 1][r] = v.y;
    At[c4 * 4 + 2][r] = v.z;
    At[c4 * 4 + 3][r] = v.w;
  }

  const int rg = tid & 15;
  const int cg = tid >> 4;
  float4 acc0a = make_float4(0.f, 0.f, 0.f, 0.f);
  float4 acc1a = make_float4(0.f, 0.f, 0.f, 0.f);
  float4 acc0b = make_float4(0.f, 0.f, 0.f, 0.f);
  float4 acc1b = make_float4(0.f, 0.f, 0.f, 0.f);

  for (int kt = 0; kt < 2; ++kt) {
    __syncthreads();
    for (int i = tid * 4; i < 64 * NOUT; i += 1024) {
      *reinterpret_cast<float4*>(&Ws[0][0] + i) =
          *reinterpret_cast<const float4*>(&W[(size_t)kt * 64 * NOUT + i]);
    }
    __syncthreads();
    #pragma unroll 8
    for (int kk = 0; kk < 64; ++kk) {
      const int k = kt * 64 + kk;
      const float2 a = *reinterpret_cast<const float2*>(&At[k][rg * 2]);
      const float4 w0 = *reinterpret_cast<const float4*>(&Ws[kk][cg * CPT]);
      acc0a.x = fmaf(a.x, w0.x, acc0a.x);
      acc0a.y = fmaf(a.x, w0.y, acc0a.y);
      acc0a.z = fmaf(a.x, w0.z, acc0a.z);
      acc0a.w = fmaf(a.x, w0.w, acc0a.w);
      acc1a.x = fmaf(a.y, w0.x, acc1a.x);
      acc1a.y = fmaf(a.y, w0.y, acc1a.y);
      acc1a.z = fmaf(a.y, w0.z, acc1a.z);
      acc1a.w = fmaf(a.y, w0.w, acc1a.w);
      if constexpr (CPT == 8) {
        const float4 w1 = *reinterpret_cast<const float4*>(&Ws[kk][cg * CPT + 4]);
        acc0b.x = fmaf(a.x, w1.x, acc0b.x);
        acc0b.y = fmaf(a.x, w1.y, acc0b.y);
        acc0b.z = fmaf(a.x, w1.z, acc0b.z);
        acc0b.w = fmaf(a.x, w1.w, acc0b.w);
        acc1b.x = fmaf(a.y, w1.x, acc1b.x);
        acc1b.y = fmaf(a.y, w1.y, acc1b.y);
        acc1b.z = fmaf(a.y, w1.z, acc1b.z);
        acc1b.w = fmaf(a.y, w1.w, acc1b.w);
      }
    }
  }

  const int gr0 = row0 + rg * 2;
  if (gr0 < M) {
    *reinterpret_cast<float4*>(&C[(size_t)gr0 * NOUT + cg * CPT]) = acc0a;
    if constexpr (CPT == 8)
      *reinterpret_cast<float4*>(&C[(size_t)gr0 * NOUT + cg * CPT + 4]) = acc0b;
  }
  if (gr0 + 1 < M) {
    *reinterpret_cast<float4*>(&C[(size_t)(gr0 + 1) * NOUT + cg * CPT]) = acc1a;
    if constexpr (CPT == 8)
      *reinterpret_cast<float4*>(&C[(size_t)(gr0 + 1) * NOUT + cg * CPT + 4]) = acc1b;
  }
}

// ---------------------------------------------------------------------------
// CSR build: histogram -> two-level exclusive scan -> fill (src sorted by dst)
// ---------------------------------------------------------------------------
__global__ __launch_bounds__(256) void count_k(const int* __restrict__ dst,
                                               int* __restrict__ counts, int E) {
  const int t = blockIdx.x * 256 + threadIdx.x;
  if (t < E) atomicAdd(&counts[dst[t]], 1);
}

// Block of 256 threads scans a 2048-element tile; writes block-local
// exclusive scan into rowptr and the tile total into bsum[blockIdx.x].
__global__ __launch_bounds__(256) void scan1_k(const int* __restrict__ counts,
                                               int* __restrict__ rowptr,
                                               int* __restrict__ bsum, int N) {
  __shared__ int ls[256];
  const int t = threadIdx.x;
  const int base = blockIdx.x * 2048 + t * 8;
  int v[8];
  if (base + 8 <= N) {
    *reinterpret_cast<int4*>(&v[0]) = *reinterpret_cast<const int4*>(&counts[base]);
    *reinterpret_cast<int4*>(&v[4]) = *reinterpret_cast<const int4*>(&counts[base + 4]);
  } else {
    #pragma unroll
    for (int j = 0; j < 8; ++j) v[j] = (base + j < N) ? counts[base + j] : 0;
  }
  int s = 0;
  #pragma unroll
  for (int j = 0; j < 8; ++j) { const int tmp = v[j]; v[j] = s; s += tmp; }
  int x = s;
  ls[t] = x;
  __syncthreads();
  for (int off = 1; off < 256; off <<= 1) {
    int y = 0;
    if (t >= off) y = ls[t - off];
    __syncthreads();
    x += y;
    ls[t] = x;
    __syncthreads();
  }
  const int excl = x - s;                 // exclusive offset of this thread in block
  #pragma unroll
  for (int j = 0; j < 8; ++j)
    if (base + j < N) rowptr[base + j] = excl + v[j];
  if (t == 255) bsum[blockIdx.x] = x;     // block total (inclusive of all)
}

// Single-wave exclusive scan of up to 64 block sums.
__global__ __launch_bounds__(64) void scan2_k(const int* __restrict__ bsum,
                                              int* __restrict__ bscan, int NB) {
  const int t = threadIdx.x;
  const int v = (t < NB) ? bsum[t] : 0;
  int x = v;
  #pragma unroll
  for (int off = 1; off < 64; off <<= 1) {
    const int y = __shfl_up(x, off, 64);
    if (t >= off) x += y;
  }
  bscan[t] = x - v;
}

// Finalize rowptr with block offsets; init cursor = rowptr.
__global__ __launch_bounds__(256) void scan3_k(int* __restrict__ rowptr,
                                               const int* __restrict__ bscan,
                                               int* __restrict__ cursor,
                                               int N, int E) {
  const int t = blockIdx.x * 256 + threadIdx.x;
  if (t < N) {
    const int r = rowptr[t] + bscan[t >> 11];
    rowptr[t] = r;
    cursor[t] = r;
  }
  if (t == 0) rowptr[N] = E;
}

__global__ __launch_bounds__(256) void fill_k(const int* __restrict__ src,
                                              const int* __restrict__ dst,
                                              int* __restrict__ cursor,
                                              int* __restrict__ col, int E) {
  const int t = blockIdx.x * 256 + threadIdx.x;
  if (t < E) {
    const int pos = atomicAdd(&cursor[dst[t]], 1);
    col[pos] = src[t];
  }
}

// ---------------------------------------------------------------------------
// Gather-aggregate, D=128: one wave per dst node, lane holds float2.
// ---------------------------------------------------------------------------
__global__ __launch_bounds__(256) void gather128_k(const float* __restrict__ H,
                                                   const int* __restrict__ rowptr,
                                                   const int* __restrict__ col,
                                                   float* __restrict__ out, int N) {
  const int w = (int)((blockIdx.x * 256u + threadIdx.x) >> 6);
  const int lane = threadIdx.x & 63;
  if (w >= N) return;
  const int beg = rowptr[w];
  const int end = rowptr[w + 1];
  float2 acc = make_float2(0.f, 0.f);
  float2 acc2 = make_float2(0.f, 0.f);
  int e = beg;
  for (; e + 2 <= end; e += 2) {
    const int s0 = col[e];
    const int s1 = col[e + 1];
    const float2 v0 = *reinterpret_cast<const float2*>(&H[(size_t)s0 * 128 + lane * 2]);
    const float2 v1 = *reinterpret_cast<const float2*>(&H[(size_t)s1 * 128 + lane * 2]);
    acc.x += v0.x;  acc.y += v0.y;
    acc2.x += v1.x; acc2.y += v1.y;
  }
  if (e < end) {
    const int s0 = col[e];
    const float2 v0 = *reinterpret_cast<const float2*>(&H[(size_t)s0 * 128 + lane * 2]);
    acc.x += v0.x; acc.y += v0.y;
  }
  acc.x += acc2.x;
  acc.y += acc2.y;
  *reinterpret_cast<float2*>(&out[(size_t)w * 128 + lane * 2]) = acc;
}

// ---------------------------------------------------------------------------
// Gather-aggregate D=64 fused with row log_softmax: lane holds 1 float.
// ---------------------------------------------------------------------------
__global__ __launch_bounds__(256) void gather64lsm_k(const float* __restrict__ H,
                                                     const int* __restrict__ rowptr,
                                                     const int* __restrict__ col,
                                                     float* __restrict__ out, int N) {
  const int w = (int)((blockIdx.x * 256u + threadIdx.x) >> 6);
  const int lane = threadIdx.x & 63;
  if (w >= N) return;
  const int beg = rowptr[w];
  const int end = rowptr[w + 1];
  float a0 = 0.f, a1 = 0.f;
  int e = beg;
  for (; e + 2 <= end; e += 2) {
    const int s0 = col[e];
    const int s1 = col[e + 1];
    a0 += H[(size_t)s0 * 64 + lane];
    a1 += H[(size_t)s1 * 64 + lane];
  }
  if (e < end) a0 += H[(size_t)col[e] * 64 + lane];
  const float v = a0 + a1;
  float m = v;
  #pragma unroll
  for (int o = 32; o > 0; o >>= 1) m = fmaxf(m, __shfl_xor(m, o, 64));
  const float ex = __expf(v - m);
  float s = ex;
  #pragma unroll
  for (int o = 32; o > 0; o >>= 1) s += __shfl_xor(s, o, 64);
  out[(size_t)w * 64 + lane] = v - m - __logf(s);
}

extern "C" void kernel_launch(void* const* d_in, const int* in_sizes, int n_in,
                              void* d_out, int out_size, void* d_ws, size_t ws_size,
                              hipStream_t stream) {
  const float* x  = (const float*)d_in[0];
  const int*   ei = (const int*)d_in[1];
  const float* W1 = (const float*)d_in[2];
  const float* W2 = (const float*)d_in[3];
  const float* W3 = (const float*)d_in[4];
  float* out = (float*)d_out;

  const int N = in_sizes[0] / KDIM;       // 100000
  const int E = in_sizes[1] / 2;          // 1600000
  const int* src = ei;
  const int* dst = ei + E;

  // Workspace layout
  float* H   = (float*)d_ws;                          // [N,128]
  float* AGG = H + (size_t)N * KDIM;                  // [N,128]
  int* col    = (int*)(AGG + (size_t)N * KDIM);       // [E]
  int* rowptr = col + E;                              // [N+1]
  int* counts = rowptr + (N + 1);                     // [N] (histogram, then cursor)
  int* bsum   = counts + N;                           // [64]
  int* bscan  = bsum + 64;                            // [64]

  const int egrid = (E + 255) / 256;
  const int nb = (N + 2047) / 2048;                   // scan tiles (49)

  // ---- CSR build (dst-sorted adjacency), reused by all 3 layers ----
  hipMemsetAsync(counts, 0, (size_t)N * sizeof(int), stream);
  count_k<<<egrid, 256, 0, stream>>>(dst, counts, E);
  scan1_k<<<nb, 256, 0, stream>>>(counts, rowptr, bsum, N);
  scan2_k<<<1, 64, 0, stream>>>(bsum, bscan, nb);
  scan3_k<<<(N + 255) / 256, 256, 0, stream>>>(rowptr, bscan, counts, N, E);
  fill_k<<<egrid, 256, 0, stream>>>(src, dst, counts, col, E);

  const int gemm_grid = (N + 31) / 32;
  const int gather_grid = (N + 3) / 4;                // 4 waves/block, 1 node/wave

  // ---- layer 1 ----
  gemm_k<128, false><<<gemm_grid, 256, 0, stream>>>(x, W1, H, N);
  gather128_k<<<gather_grid, 256, 0, stream>>>(H, rowptr, col, AGG, N);

  // ---- layer 2 ----
  gemm_k<128, true><<<gemm_grid, 256, 0, stream>>>(AGG, W2, H, N);
  gather128_k<<<gather_grid, 256, 0, stream>>>(H, rowptr, col, AGG, N);

  // ---- layer 3 (+ fused log_softmax) ----
  gemm_k<64, true><<<gemm_grid, 256, 0, stream>>>(AGG, W3, H, N);
  gather64lsm_k<<<gather_grid, 256, 0, stream>>>(H, rowptr, col, out, N);
}

// Round 4
// 577.380 us; speedup vs baseline: 11.9788x; 1.1947x over previous
//
#include <hip/hip_runtime.h>
#include <hip/hip_bf16.h>

#define KDIM 128

// bf16 pack/unpack via explicit bit ops (ROCm header API names vary).
static __device__ __forceinline__ unsigned short f2bf(float f) {
  unsigned u = __float_as_uint(f);
  u += 0x7fffu + ((u >> 16) & 1u);        // round-to-nearest-even
  return (unsigned short)(u >> 16);
}
static __device__ __forceinline__ unsigned pack_bf16x2(float a, float b) {
  return (unsigned)f2bf(a) | ((unsigned)f2bf(b) << 16);
}
static __device__ __forceinline__ float bf2f(unsigned short s) {
  return __uint_as_float((unsigned)s << 16);
}
static __device__ __forceinline__ float2 unpack_bf16x2(unsigned u) {
  return make_float2(__uint_as_float(u << 16), __uint_as_float(u & 0xffff0000u));
}

// ---------------------------------------------------------------------------
// GEMM: C[M,NOUT] = act(A[M,128]) @ W[128,NOUT], act = ReLU if RELU.
// A,W f32; C written as bf16 (feeds the gather).
// ---------------------------------------------------------------------------
template<int NOUT, bool RELU>
__global__ __launch_bounds__(256) void gemm_k(const float* __restrict__ A,
                                              const float* __restrict__ W,
                                              unsigned short* __restrict__ C, int M) {
  constexpr int BM = 32;
  constexpr int CPT = NOUT / 16;          // 8 for NOUT=128, 4 for NOUT=64
  __shared__ float Ws[64][NOUT];          // half-K slab of W
  __shared__ float At[KDIM][BM + 2];      // A tile, transposed, padded
  const int tid = threadIdx.x;
  const int row0 = blockIdx.x * BM;

  for (int i = tid; i < BM * (KDIM / 4); i += 256) {
    const int r = i / (KDIM / 4);
    const int c4 = i % (KDIM / 4);
    const int gr = row0 + r;
    float4 v = make_float4(0.f, 0.f, 0.f, 0.f);
    if (gr < M) v = *reinterpret_cast<const float4*>(&A[(size_t)gr * KDIM + c4 * 4]);
    if (RELU) {
      v.x = fmaxf(v.x, 0.f); v.y = fmaxf(v.y, 0.f);
      v.z = fmaxf(v.z, 0.f); v.w = fmaxf(v.w, 0.f);
    }
    At[c4 * 4 + 0][r] = v.x;
    At[c4 * 4 + 1][r] = v.y;
    At[c4 * 4 + 2][r] = v.z;
    At[c4 * 4 + 3][r] = v.w;
  }

  const int rg = tid & 15;
  const int cg = tid >> 4;
  float4 acc0a = make_float4(0.f, 0.f, 0.f, 0.f);
  float4 acc1a = make_float4(0.f, 0.f, 0.f, 0.f);
  float4 acc0b = make_float4(0.f, 0.f, 0.f, 0.f);
  float4 acc1b = make_float4(0.f, 0.f, 0.f, 0.f);

  for (int kt = 0; kt < 2; ++kt) {
    __syncthreads();
    for (int i = tid * 4; i < 64 * NOUT; i += 1024) {
      *reinterpret_cast<float4*>(&Ws[0][0] + i) =
          *reinterpret_cast<const float4*>(&W[(size_t)kt * 64 * NOUT + i]);
    }
    __syncthreads();
    #pragma unroll 8
    for (int kk = 0; kk < 64; ++kk) {
      const int k = kt * 64 + kk;
      const float2 a = *reinterpret_cast<const float2*>(&At[k][rg * 2]);
      const float4 w0 = *reinterpret_cast<const float4*>(&Ws[kk][cg * CPT]);
      acc0a.x = fmaf(a.x, w0.x, acc0a.x);
      acc0a.y = fmaf(a.x, w0.y, acc0a.y);
      acc0a.z = fmaf(a.x, w0.z, acc0a.z);
      acc0a.w = fmaf(a.x, w0.w, acc0a.w);
      acc1a.x = fmaf(a.y, w0.x, acc1a.x);
      acc1a.y = fmaf(a.y, w0.y, acc1a.y);
      acc1a.z = fmaf(a.y, w0.z, acc1a.z);
      acc1a.w = fmaf(a.y, w0.w, acc1a.w);
      if constexpr (CPT == 8) {
        const float4 w1 = *reinterpret_cast<const float4*>(&Ws[kk][cg * CPT + 4]);
        acc0b.x = fmaf(a.x, w1.x, acc0b.x);
        acc0b.y = fmaf(a.x, w1.y, acc0b.y);
        acc0b.z = fmaf(a.x, w1.z, acc0b.z);
        acc0b.w = fmaf(a.x, w1.w, acc0b.w);
        acc1b.x = fmaf(a.y, w1.x, acc1b.x);
        acc1b.y = fmaf(a.y, w1.y, acc1b.y);
        acc1b.z = fmaf(a.y, w1.z, acc1b.z);
        acc1b.w = fmaf(a.y, w1.w, acc1b.w);
      }
    }
  }

  const int gr0 = row0 + rg * 2;
  if constexpr (CPT == 8) {
    const uint4 p0 = make_uint4(pack_bf16x2(acc0a.x, acc0a.y), pack_bf16x2(acc0a.z, acc0a.w),
                                pack_bf16x2(acc0b.x, acc0b.y), pack_bf16x2(acc0b.z, acc0b.w));
    const uint4 p1 = make_uint4(pack_bf16x2(acc1a.x, acc1a.y), pack_bf16x2(acc1a.z, acc1a.w),
                                pack_bf16x2(acc1b.x, acc1b.y), pack_bf16x2(acc1b.z, acc1b.w));
    if (gr0 < M)
      *reinterpret_cast<uint4*>(&C[(size_t)gr0 * NOUT + cg * CPT]) = p0;
    if (gr0 + 1 < M)
      *reinterpret_cast<uint4*>(&C[(size_t)(gr0 + 1) * NOUT + cg * CPT]) = p1;
  } else {
    const uint2 p0 = make_uint2(pack_bf16x2(acc0a.x, acc0a.y), pack_bf16x2(acc0a.z, acc0a.w));
    const uint2 p1 = make_uint2(pack_bf16x2(acc1a.x, acc1a.y), pack_bf16x2(acc1a.z, acc1a.w));
    if (gr0 < M)
      *reinterpret_cast<uint2*>(&C[(size_t)gr0 * NOUT + cg * CPT]) = p0;
    if (gr0 + 1 < M)
      *reinterpret_cast<uint2*>(&C[(size_t)(gr0 + 1) * NOUT + cg * CPT]) = p1;
  }
}

// ---------------------------------------------------------------------------
// CSR build: histogram -> two-level exclusive scan -> fill (src sorted by dst)
// ---------------------------------------------------------------------------
__global__ __launch_bounds__(256) void count_k(const int* __restrict__ dst,
                                               int* __restrict__ counts, int E) {
  const int t = blockIdx.x * 256 + threadIdx.x;
  if (t < E) atomicAdd(&counts[dst[t]], 1);
}

__global__ __launch_bounds__(256) void scan1_k(const int* __restrict__ counts,
                                               int* __restrict__ rowptr,
                                               int* __restrict__ bsum, int N) {
  __shared__ int ls[256];
  const int t = threadIdx.x;
  const int base = blockIdx.x * 2048 + t * 8;
  int v[8];
  if (base + 8 <= N) {
    *reinterpret_cast<int4*>(&v[0]) = *reinterpret_cast<const int4*>(&counts[base]);
    *reinterpret_cast<int4*>(&v[4]) = *reinterpret_cast<const int4*>(&counts[base + 4]);
  } else {
    #pragma unroll
    for (int j = 0; j < 8; ++j) v[j] = (base + j < N) ? counts[base + j] : 0;
  }
  int s = 0;
  #pragma unroll
  for (int j = 0; j < 8; ++j) { const int tmp = v[j]; v[j] = s; s += tmp; }
  int x = s;
  ls[t] = x;
  __syncthreads();
  for (int off = 1; off < 256; off <<= 1) {
    int y = 0;
    if (t >= off) y = ls[t - off];
    __syncthreads();
    x += y;
    ls[t] = x;
    __syncthreads();
  }
  const int excl = x - s;
  #pragma unroll
  for (int j = 0; j < 8; ++j)
    if (base + j < N) rowptr[base + j] = excl + v[j];
  if (t == 255) bsum[blockIdx.x] = x;
}

__global__ __launch_bounds__(64) void scan2_k(const int* __restrict__ bsum,
                                              int* __restrict__ bscan, int NB) {
  const int t = threadIdx.x;
  const int v = (t < NB) ? bsum[t] : 0;
  int x = v;
  #pragma unroll
  for (int off = 1; off < 64; off <<= 1) {
    const int y = __shfl_up(x, off, 64);
    if (t >= off) x += y;
  }
  bscan[t] = x - v;
}

__global__ __launch_bounds__(256) void scan3_k(int* __restrict__ rowptr,
                                               const int* __restrict__ bscan,
                                               int* __restrict__ cursor,
                                               int N, int E) {
  const int t = blockIdx.x * 256 + threadIdx.x;
  if (t < N) {
    const int r = rowptr[t] + bscan[t >> 11];
    rowptr[t] = r;
    cursor[t] = r;
  }
  if (t == 0) rowptr[N] = E;
}

__global__ __launch_bounds__(256) void fill_k(const int* __restrict__ src,
                                              const int* __restrict__ dst,
                                              int* __restrict__ cursor,
                                              int* __restrict__ col, int E) {
  const int t = blockIdx.x * 256 + threadIdx.x;
  if (t < E) {
    const int pos = atomicAdd(&cursor[dst[t]], 1);
    col[pos] = src[t];
  }
}

// ---------------------------------------------------------------------------
// Gather-aggregate, D=128 bf16 rows: one wave per dst node, lane holds 1 dword
// (2 bf16). Accumulate f32, write AGG f32.
// ---------------------------------------------------------------------------
__global__ __launch_bounds__(256) void gather128_k(const unsigned* __restrict__ Hu,
                                                   const int* __restrict__ rowptr,
                                                   const int* __restrict__ col,
                                                   float* __restrict__ out, int N) {
  const int w = (int)((blockIdx.x * 256u + threadIdx.x) >> 6);
  const int lane = threadIdx.x & 63;
  if (w >= N) return;
  const int beg = rowptr[w];
  const int end = rowptr[w + 1];
  float2 a0 = make_float2(0.f, 0.f), a1 = make_float2(0.f, 0.f);
  float2 a2 = make_float2(0.f, 0.f), a3 = make_float2(0.f, 0.f);
  int e = beg;
  for (; e + 4 <= end; e += 4) {
    const int s0 = col[e],     s1 = col[e + 1];
    const int s2 = col[e + 2], s3 = col[e + 3];
    const unsigned u0 = Hu[(size_t)s0 * 64 + lane];
    const unsigned u1 = Hu[(size_t)s1 * 64 + lane];
    const unsigned u2 = Hu[(size_t)s2 * 64 + lane];
    const unsigned u3 = Hu[(size_t)s3 * 64 + lane];
    const float2 v0 = unpack_bf16x2(u0), v1 = unpack_bf16x2(u1);
    const float2 v2 = unpack_bf16x2(u2), v3 = unpack_bf16x2(u3);
    a0.x += v0.x; a0.y += v0.y;
    a1.x += v1.x; a1.y += v1.y;
    a2.x += v2.x; a2.y += v2.y;
    a3.x += v3.x; a3.y += v3.y;
  }
  for (; e < end; ++e) {
    const float2 v = unpack_bf16x2(Hu[(size_t)col[e] * 64 + lane]);
    a0.x += v.x; a0.y += v.y;
  }
  a0.x += a1.x + a2.x + a3.x;
  a0.y += a1.y + a2.y + a3.y;
  *reinterpret_cast<float2*>(&out[(size_t)w * 128 + lane * 2]) = a0;
}

// ---------------------------------------------------------------------------
// Gather-aggregate D=64 bf16 fused with row log_softmax: lane holds 1 value.
// ---------------------------------------------------------------------------
__global__ __launch_bounds__(256) void gather64lsm_k(const unsigned short* __restrict__ Hs,
                                                     const int* __restrict__ rowptr,
                                                     const int* __restrict__ col,
                                                     float* __restrict__ out, int N) {
  const int w = (int)((blockIdx.x * 256u + threadIdx.x) >> 6);
  const int lane = threadIdx.x & 63;
  if (w >= N) return;
  const int beg = rowptr[w];
  const int end = rowptr[w + 1];
  float a0 = 0.f, a1 = 0.f, a2 = 0.f, a3 = 0.f;
  int e = beg;
  for (; e + 4 <= end; e += 4) {
    a0 += bf2f(Hs[(size_t)col[e] * 64 + lane]);
    a1 += bf2f(Hs[(size_t)col[e + 1] * 64 + lane]);
    a2 += bf2f(Hs[(size_t)col[e + 2] * 64 + lane]);
    a3 += bf2f(Hs[(size_t)col[e + 3] * 64 + lane]);
  }
  for (; e < end; ++e) a0 += bf2f(Hs[(size_t)col[e] * 64 + lane]);
  const float v = (a0 + a1) + (a2 + a3);
  float m = v;
  #pragma unroll
  for (int o = 32; o > 0; o >>= 1) m = fmaxf(m, __shfl_xor(m, o, 64));
  const float ex = __expf(v - m);
  float s = ex;
  #pragma unroll
  for (int o = 32; o > 0; o >>= 1) s += __shfl_xor(s, o, 64);
  out[(size_t)w * 64 + lane] = v - m - __logf(s);
}

extern "C" void kernel_launch(void* const* d_in, const int* in_sizes, int n_in,
                              void* d_out, int out_size, void* d_ws, size_t ws_size,
                              hipStream_t stream) {
  const float* x  = (const float*)d_in[0];
  const int*   ei = (const int*)d_in[1];
  const float* W1 = (const float*)d_in[2];
  const float* W2 = (const float*)d_in[3];
  const float* W3 = (const float*)d_in[4];
  float* out = (float*)d_out;

  const int N = in_sizes[0] / KDIM;       // 100000
  const int E = in_sizes[1] / 2;          // 1600000
  const int* src = ei;
  const int* dst = ei + E;

  // Workspace layout
  unsigned short* H = (unsigned short*)d_ws;            // [N,128] bf16
  float* AGG = (float*)(H + (size_t)N * KDIM);          // [N,128] f32
  int* col    = (int*)(AGG + (size_t)N * KDIM);         // [E]
  int* rowptr = col + E;                                // [N+1]
  int* counts = rowptr + (N + 1);                       // [N]
  int* bsum   = counts + N;                             // [64]
  int* bscan  = bsum + 64;                              // [64]

  const int egrid = (E + 255) / 256;
  const int nb = (N + 2047) / 2048;

  // ---- CSR build (dst-sorted adjacency), reused by all 3 layers ----
  (void)hipMemsetAsync(counts, 0, (size_t)N * sizeof(int), stream);
  count_k<<<egrid, 256, 0, stream>>>(dst, counts, E);
  scan1_k<<<nb, 256, 0, stream>>>(counts, rowptr, bsum, N);
  scan2_k<<<1, 64, 0, stream>>>(bsum, bscan, nb);
  scan3_k<<<(N + 255) / 256, 256, 0, stream>>>(rowptr, bscan, counts, N, E);
  fill_k<<<egrid, 256, 0, stream>>>(src, dst, counts, col, E);

  const int gemm_grid = (N + 31) / 32;
  const int gather_grid = (N + 3) / 4;

  // ---- layer 1 ----
  gemm_k<128, false><<<gemm_grid, 256, 0, stream>>>(x, W1, H, N);
  gather128_k<<<gather_grid, 256, 0, stream>>>((const unsigned*)H, rowptr, col, AGG, N);

  // ---- layer 2 ----
  gemm_k<128, true><<<gemm_grid, 256, 0, stream>>>(AGG, W2, H, N);
  gather128_k<<<gather_grid, 256, 0, stream>>>((const unsigned*)H, rowptr, col, AGG, N);

  // ---- layer 3 (+ fused log_softmax) ----
  gemm_k<64, true><<<gemm_grid, 256, 0, stream>>>(AGG, W3, H, N);
  gather64lsm_k<<<gather_grid, 256, 0, stream>>>((const unsigned short*)H, rowptr, col, out, N);
}

// Round 5
// 457.798 us; speedup vs baseline: 15.1078x; 1.2612x over previous
//
#include <hip/hip_runtime.h>
#include <hip/hip_bf16.h>

#define KDIM 128

typedef __attribute__((ext_vector_type(8))) __bf16 bf16x8;
typedef __attribute__((ext_vector_type(4))) float f32x4;

// bf16 pack/unpack via explicit bit ops (ROCm header API names vary).
static __device__ __forceinline__ unsigned short f2bf(float f) {
  unsigned u = __float_as_uint(f);
  u += 0x7fffu + ((u >> 16) & 1u);        // round-to-nearest-even
  return (unsigned short)(u >> 16);
}
static __device__ __forceinline__ unsigned pack_bf16x2(float a, float b) {
  return (unsigned)f2bf(a) | ((unsigned)f2bf(b) << 16);
}
static __device__ __forceinline__ float bf2f(unsigned short s) {
  return __uint_as_float((unsigned)s << 16);
}
static __device__ __forceinline__ float2 unpack_bf16x2(unsigned u) {
  return make_float2(__uint_as_float(u << 16), __uint_as_float(u & 0xffff0000u));
}
// ReLU on a packed pair of bf16 (zero any half with sign bit set).
static __device__ __forceinline__ unsigned relu2(unsigned u) {
  unsigned r = u;
  if (u & 0x00008000u) r &= 0xffff0000u;
  if (u & 0x80000000u) r &= 0x0000ffffu;
  return r;
}

// ---------------------------------------------------------------------------
// W transpose + bf16 cast: Wt[n][k] = bf16(W[k][n]). K=128 fixed.
// ---------------------------------------------------------------------------
__global__ __launch_bounds__(256) void wtrans_k(const float* __restrict__ W,
                                                unsigned short* __restrict__ Wt,
                                                int NOUT) {
  const int t = blockIdx.x * 256 + threadIdx.x;
  if (t >= NOUT * KDIM) return;
  const int n = t >> 7;                   // t / 128
  const int k = t & 127;                  // t % 128
  Wt[t] = f2bf(W[k * NOUT + n]);
}

// ---------------------------------------------------------------------------
// MFMA GEMM: C[M,NOUT](bf16) = act(A[M,128]) @ W, W given as Wt[n][k] bf16.
// Block: 512 threads = 8 waves, BM=128 (16 rows/wave). mfma_f32_16x16x32_bf16.
// A fragments loaded directly from global (16B/lane); W staged in LDS.
// AF32: A is f32 [M,128]. else: A is packed bf16 pairs (unsigned [M,64]).
// ---------------------------------------------------------------------------
template<int NOUT, bool AF32, bool RELU>
__global__ __launch_bounds__(512) void gemm_mfma_k(const void* __restrict__ Av,
                                                   const unsigned short* __restrict__ Wt,
                                                   unsigned short* __restrict__ C, int M) {
  constexpr int NT = NOUT / 16;           // n-tiles per wave
  __shared__ unsigned short Ws[NOUT][136];  // [n][k], +8 pad breaks 16-way conflicts

  const int tid = threadIdx.x;
  // Stage Wt -> LDS: coalesced uint4, conflict-free (consecutive 16B writes).
  for (int i = tid; i < NOUT * 16; i += 512) {
    const int n = i >> 4, k8 = i & 15;
    const uint4 v = *reinterpret_cast<const uint4*>(&Wt[n * KDIM + k8 * 8]);
    *reinterpret_cast<uint4*>(&Ws[n][k8 * 8]) = v;
  }

  const int wv = tid >> 6;                // wave 0..7
  const int l  = tid & 63;
  const int am = l & 15;                  // A row within 16-row tile / B col / C col
  const int kb = l >> 4;                  // k-block 0..3
  const int arow_g = blockIdx.x * 128 + wv * 16 + am;
  const bool valid = arow_g < M;
  const int arow = valid ? arow_g : 0;

  // A fragments for all 4 k-steps (k = ks*32 + kb*8 .. +7), in registers.
  uint4 afr[4];
  if constexpr (AF32) {
    const float* A = (const float*)Av;
    #pragma unroll
    for (int ks = 0; ks < 4; ++ks) {
      const float4 lo = *reinterpret_cast<const float4*>(&A[(size_t)arow * 128 + ks * 32 + kb * 8]);
      const float4 hi = *reinterpret_cast<const float4*>(&A[(size_t)arow * 128 + ks * 32 + kb * 8 + 4]);
      afr[ks] = make_uint4(pack_bf16x2(lo.x, lo.y), pack_bf16x2(lo.z, lo.w),
                           pack_bf16x2(hi.x, hi.y), pack_bf16x2(hi.z, hi.w));
    }
  } else {
    const unsigned* A = (const unsigned*)Av;
    #pragma unroll
    for (int ks = 0; ks < 4; ++ks) {
      uint4 u = *reinterpret_cast<const uint4*>(&A[(size_t)arow * 64 + ks * 16 + kb * 4]);
      if constexpr (RELU) {
        u.x = relu2(u.x); u.y = relu2(u.y); u.z = relu2(u.z); u.w = relu2(u.w);
      }
      afr[ks] = u;
    }
  }
  if (!valid) {
    afr[0] = make_uint4(0, 0, 0, 0); afr[1] = afr[0];
    afr[2] = afr[0];                 afr[3] = afr[0];
  }

  f32x4 acc[NT];
  #pragma unroll
  for (int nt = 0; nt < NT; ++nt) {
    acc[nt][0] = 0.f; acc[nt][1] = 0.f; acc[nt][2] = 0.f; acc[nt][3] = 0.f;
  }

  __syncthreads();
  #pragma unroll
  for (int ks = 0; ks < 4; ++ks) {
    const bf16x8 a = __builtin_bit_cast(bf16x8, afr[ks]);
    #pragma unroll
    for (int nt = 0; nt < NT; ++nt) {
      const uint4 bv = *reinterpret_cast<const uint4*>(&Ws[nt * 16 + am][ks * 32 + kb * 8]);
      acc[nt] = __builtin_amdgcn_mfma_f32_16x16x32_bf16(
          a, __builtin_bit_cast(bf16x8, bv), acc[nt], 0, 0, 0);
    }
  }

  // C/D layout: col = lane&15 (=am), row = 4*(lane>>4) (=kb*4) + reg.
  const int crow0 = blockIdx.x * 128 + wv * 16 + kb * 4;
  #pragma unroll
  for (int nt = 0; nt < NT; ++nt) {
    #pragma unroll
    for (int r = 0; r < 4; ++r) {
      const int rr = crow0 + r;
      if (rr < M) C[(size_t)rr * NOUT + nt * 16 + am] = f2bf(acc[nt][r]);
    }
  }
}

// ---------------------------------------------------------------------------
// CSR build: histogram -> two-level exclusive scan -> fill (src sorted by dst)
// ---------------------------------------------------------------------------
__global__ __launch_bounds__(256) void count_k(const int* __restrict__ dst,
                                               int* __restrict__ counts, int E) {
  const int t = blockIdx.x * 256 + threadIdx.x;
  if (t < E) atomicAdd(&counts[dst[t]], 1);
}

__global__ __launch_bounds__(256) void scan1_k(const int* __restrict__ counts,
                                               int* __restrict__ rowptr,
                                               int* __restrict__ bsum, int N) {
  __shared__ int ls[256];
  const int t = threadIdx.x;
  const int base = blockIdx.x * 2048 + t * 8;
  int v[8];
  if (base + 8 <= N) {
    *reinterpret_cast<int4*>(&v[0]) = *reinterpret_cast<const int4*>(&counts[base]);
    *reinterpret_cast<int4*>(&v[4]) = *reinterpret_cast<const int4*>(&counts[base + 4]);
  } else {
    #pragma unroll
    for (int j = 0; j < 8; ++j) v[j] = (base + j < N) ? counts[base + j] : 0;
  }
  int s = 0;
  #pragma unroll
  for (int j = 0; j < 8; ++j) { const int tmp = v[j]; v[j] = s; s += tmp; }
  int x = s;
  ls[t] = x;
  __syncthreads();
  for (int off = 1; off < 256; off <<= 1) {
    int y = 0;
    if (t >= off) y = ls[t - off];
    __syncthreads();
    x += y;
    ls[t] = x;
    __syncthreads();
  }
  const int excl = x - s;
  #pragma unroll
  for (int j = 0; j < 8; ++j)
    if (base + j < N) rowptr[base + j] = excl + v[j];
  if (t == 255) bsum[blockIdx.x] = x;
}

__global__ __launch_bounds__(64) void scan2_k(const int* __restrict__ bsum,
                                              int* __restrict__ bscan, int NB) {
  const int t = threadIdx.x;
  const int v = (t < NB) ? bsum[t] : 0;
  int x = v;
  #pragma unroll
  for (int off = 1; off < 64; off <<= 1) {
    const int y = __shfl_up(x, off, 64);
    if (t >= off) x += y;
  }
  bscan[t] = x - v;
}

__global__ __launch_bounds__(256) void scan3_k(int* __restrict__ rowptr,
                                               const int* __restrict__ bscan,
                                               int* __restrict__ cursor,
                                               int N, int E) {
  const int t = blockIdx.x * 256 + threadIdx.x;
  if (t < N) {
    const int r = rowptr[t] + bscan[t >> 11];
    rowptr[t] = r;
    cursor[t] = r;
  }
  if (t == 0) rowptr[N] = E;
}

__global__ __launch_bounds__(256) void fill_k(const int* __restrict__ src,
                                              const int* __restrict__ dst,
                                              int* __restrict__ cursor,
                                              int* __restrict__ col, int E) {
  const int t = blockIdx.x * 256 + threadIdx.x;
  if (t < E) {
    const int pos = atomicAdd(&cursor[dst[t]], 1);
    col[pos] = src[t];
  }
}

// ---------------------------------------------------------------------------
// Gather-aggregate, D=128 bf16 rows: one wave per dst node, lane holds 1 dword
// (2 bf16). Accumulate f32, write packed bf16 (feeds next MFMA GEMM).
// ---------------------------------------------------------------------------
__global__ __launch_bounds__(256) void gather128_k(const unsigned* __restrict__ Hu,
                                                   const int* __restrict__ rowptr,
                                                   const int* __restrict__ col,
                                                   unsigned* __restrict__ out, int N) {
  const int w = (int)((blockIdx.x * 256u + threadIdx.x) >> 6);
  const int lane = threadIdx.x & 63;
  if (w >= N) return;
  const int beg = rowptr[w];
  const int end = rowptr[w + 1];
  float2 a0 = make_float2(0.f, 0.f), a1 = make_float2(0.f, 0.f);
  float2 a2 = make_float2(0.f, 0.f), a3 = make_float2(0.f, 0.f);
  int e = beg;
  for (; e + 4 <= end; e += 4) {
    const int s0 = col[e],     s1 = col[e + 1];
    const int s2 = col[e + 2], s3 = col[e + 3];
    const unsigned u0 = Hu[(size_t)s0 * 64 + lane];
    const unsigned u1 = Hu[(size_t)s1 * 64 + lane];
    const unsigned u2 = Hu[(size_t)s2 * 64 + lane];
    const unsigned u3 = Hu[(size_t)s3 * 64 + lane];
    const float2 v0 = unpack_bf16x2(u0), v1 = unpack_bf16x2(u1);
    const float2 v2 = unpack_bf16x2(u2), v3 = unpack_bf16x2(u3);
    a0.x += v0.x; a0.y += v0.y;
    a1.x += v1.x; a1.y += v1.y;
    a2.x += v2.x; a2.y += v2.y;
    a3.x += v3.x; a3.y += v3.y;
  }
  for (; e < end; ++e) {
    const float2 v = unpack_bf16x2(Hu[(size_t)col[e] * 64 + lane]);
    a0.x += v.x; a0.y += v.y;
  }
  a0.x += a1.x + a2.x + a3.x;
  a0.y += a1.y + a2.y + a3.y;
  out[(size_t)w * 64 + lane] = pack_bf16x2(a0.x, a0.y);
}

// ---------------------------------------------------------------------------
// Gather-aggregate D=64 bf16 fused with row log_softmax: lane holds 1 value.
// ---------------------------------------------------------------------------
__global__ __launch_bounds__(256) void gather64lsm_k(const unsigned short* __restrict__ Hs,
                                                     const int* __restrict__ rowptr,
                                                     const int* __restrict__ col,
                                                     float* __restrict__ out, int N) {
  const int w = (int)((blockIdx.x * 256u + threadIdx.x) >> 6);
  const int lane = threadIdx.x & 63;
  if (w >= N) return;
  const int beg = rowptr[w];
  const int end = rowptr[w + 1];
  float a0 = 0.f, a1 = 0.f, a2 = 0.f, a3 = 0.f;
  int e = beg;
  for (; e + 4 <= end; e += 4) {
    a0 += bf2f(Hs[(size_t)col[e] * 64 + lane]);
    a1 += bf2f(Hs[(size_t)col[e + 1] * 64 + lane]);
    a2 += bf2f(Hs[(size_t)col[e + 2] * 64 + lane]);
    a3 += bf2f(Hs[(size_t)col[e + 3] * 64 + lane]);
  }
  for (; e < end; ++e) a0 += bf2f(Hs[(size_t)col[e] * 64 + lane]);
  const float v = (a0 + a1) + (a2 + a3);
  float m = v;
  #pragma unroll
  for (int o = 32; o > 0; o >>= 1) m = fmaxf(m, __shfl_xor(m, o, 64));
  const float ex = __expf(v - m);
  float s = ex;
  #pragma unroll
  for (int o = 32; o > 0; o >>= 1) s += __shfl_xor(s, o, 64);
  out[(size_t)w * 64 + lane] = v - m - __logf(s);
}

extern "C" void kernel_launch(void* const* d_in, const int* in_sizes, int n_in,
                              void* d_out, int out_size, void* d_ws, size_t ws_size,
                              hipStream_t stream) {
  const float* x  = (const float*)d_in[0];
  const int*   ei = (const int*)d_in[1];
  const float* W1 = (const float*)d_in[2];
  const float* W2 = (const float*)d_in[3];
  const float* W3 = (const float*)d_in[4];
  float* out = (float*)d_out;

  const int N = in_sizes[0] / KDIM;       // 100000
  const int E = in_sizes[1] / 2;          // 1600000
  const int* src = ei;
  const int* dst = ei + E;

  // Workspace layout
  unsigned short* H = (unsigned short*)d_ws;            // [N,128] bf16
  unsigned* AGGp = (unsigned*)(H + (size_t)N * KDIM);   // [N,64] packed bf16 pairs
  unsigned short* Wt1 = (unsigned short*)(AGGp + (size_t)N * 64);  // [128,128]
  unsigned short* Wt2 = Wt1 + 128 * 128;                // [128,128]
  unsigned short* Wt3 = Wt2 + 128 * 128;                // [64,128]
  int* col    = (int*)(Wt3 + 64 * 128);                 // [E]
  int* rowptr = col + E;                                // [N+1]
  int* counts = rowptr + (N + 1);                       // [N]
  int* bsum   = counts + N;                             // [64]
  int* bscan  = bsum + 64;                              // [64]

  const int egrid = (E + 255) / 256;
  const int nb = (N + 2047) / 2048;

  // ---- W transposes (tiny, once) ----
  wtrans_k<<<(128 * 128 + 255) / 256, 256, 0, stream>>>(W1, Wt1, 128);
  wtrans_k<<<(128 * 128 + 255) / 256, 256, 0, stream>>>(W2, Wt2, 128);
  wtrans_k<<<(64 * 128 + 255) / 256, 256, 0, stream>>>(W3, Wt3, 64);

  // ---- CSR build (dst-sorted adjacency), reused by all 3 layers ----
  (void)hipMemsetAsync(counts, 0, (size_t)N * sizeof(int), stream);
  count_k<<<egrid, 256, 0, stream>>>(dst, counts, E);
  scan1_k<<<nb, 256, 0, stream>>>(counts, rowptr, bsum, N);
  scan2_k<<<1, 64, 0, stream>>>(bsum, bscan, nb);
  scan3_k<<<(N + 255) / 256, 256, 0, stream>>>(rowptr, bscan, counts, N, E);
  fill_k<<<egrid, 256, 0, stream>>>(src, dst, counts, col, E);

  const int gemm_grid = (N + 127) / 128;
  const int gather_grid = (N + 3) / 4;

  // ---- layer 1 ----
  gemm_mfma_k<128, true, false><<<gemm_grid, 512, 0, stream>>>(x, Wt1, H, N);
  gather128_k<<<gather_grid, 256, 0, stream>>>((const unsigned*)H, rowptr, col, AGGp, N);

  // ---- layer 2 ----
  gemm_mfma_k<128, false, true><<<gemm_grid, 512, 0, stream>>>(AGGp, Wt2, H, N);
  gather128_k<<<gather_grid, 256, 0, stream>>>((const unsigned*)H, rowptr, col, AGGp, N);

  // ---- layer 3 (+ fused log_softmax) ----
  gemm_mfma_k<64, false, true><<<gemm_grid, 512, 0, stream>>>(AGGp, Wt3, H, N);
  gather64lsm_k<<<gather_grid, 256, 0, stream>>>((const unsigned short*)H, rowptr, col, out, N);
}

// Round 6
// 296.448 us; speedup vs baseline: 23.3306x; 1.5443x over previous
//
#include <hip/hip_runtime.h>
#include <hip/hip_bf16.h>

#define KDIM 128

typedef __attribute__((ext_vector_type(8))) __bf16 bf16x8;
typedef __attribute__((ext_vector_type(4))) float f32x4;

// bf16 pack/unpack via explicit bit ops (ROCm header API names vary).
static __device__ __forceinline__ unsigned short f2bf(float f) {
  unsigned u = __float_as_uint(f);
  u += 0x7fffu + ((u >> 16) & 1u);        // round-to-nearest-even
  return (unsigned short)(u >> 16);
}
static __device__ __forceinline__ unsigned pack_bf16x2(float a, float b) {
  return (unsigned)f2bf(a) | ((unsigned)f2bf(b) << 16);
}
static __device__ __forceinline__ float bf2f(unsigned short s) {
  return __uint_as_float((unsigned)s << 16);
}
static __device__ __forceinline__ float2 unpack_bf16x2(unsigned u) {
  return make_float2(__uint_as_float(u << 16), __uint_as_float(u & 0xffff0000u));
}
// ReLU on a packed pair of bf16 (zero any half with sign bit set).
static __device__ __forceinline__ unsigned relu2(unsigned u) {
  unsigned r = u;
  if (u & 0x00008000u) r &= 0xffff0000u;
  if (u & 0x80000000u) r &= 0x0000ffffu;
  return r;
}

// ---------------------------------------------------------------------------
// W transpose + bf16 cast: Wt[n][k] = bf16(W[k][n]). K=128 fixed.
// ---------------------------------------------------------------------------
__global__ __launch_bounds__(256) void wtrans_k(const float* __restrict__ W,
                                                unsigned short* __restrict__ Wt,
                                                int NOUT) {
  const int t = blockIdx.x * 256 + threadIdx.x;
  if (t >= NOUT * KDIM) return;
  const int n = t >> 7;                   // t / 128
  const int k = t & 127;                  // t % 128
  Wt[t] = f2bf(W[k * NOUT + n]);
}

// ---------------------------------------------------------------------------
// MFMA GEMM: C[M,NOUT](bf16) = act(A[M,128]) @ W, W given as Wt[n][k] bf16.
// Block: 512 threads = 8 waves, BM=128 (16 rows/wave). mfma_f32_16x16x32_bf16.
// ---------------------------------------------------------------------------
template<int NOUT, bool AF32, bool RELU>
__global__ __launch_bounds__(512) void gemm_mfma_k(const void* __restrict__ Av,
                                                   const unsigned short* __restrict__ Wt,
                                                   unsigned short* __restrict__ C, int M) {
  constexpr int NT = NOUT / 16;           // n-tiles per wave
  __shared__ unsigned short Ws[NOUT][136];  // [n][k], +8 pad breaks conflicts

  const int tid = threadIdx.x;
  for (int i = tid; i < NOUT * 16; i += 512) {
    const int n = i >> 4, k8 = i & 15;
    const uint4 v = *reinterpret_cast<const uint4*>(&Wt[n * KDIM + k8 * 8]);
    *reinterpret_cast<uint4*>(&Ws[n][k8 * 8]) = v;
  }

  const int wv = tid >> 6;                // wave 0..7
  const int l  = tid & 63;
  const int am = l & 15;                  // A row within 16-row tile / C col
  const int kb = l >> 4;                  // k-block 0..3
  const int arow_g = blockIdx.x * 128 + wv * 16 + am;
  const bool valid = arow_g < M;
  const int arow = valid ? arow_g : 0;

  uint4 afr[4];
  if constexpr (AF32) {
    const float* A = (const float*)Av;
    #pragma unroll
    for (int ks = 0; ks < 4; ++ks) {
      const float4 lo = *reinterpret_cast<const float4*>(&A[(size_t)arow * 128 + ks * 32 + kb * 8]);
      const float4 hi = *reinterpret_cast<const float4*>(&A[(size_t)arow * 128 + ks * 32 + kb * 8 + 4]);
      afr[ks] = make_uint4(pack_bf16x2(lo.x, lo.y), pack_bf16x2(lo.z, lo.w),
                           pack_bf16x2(hi.x, hi.y), pack_bf16x2(hi.z, hi.w));
    }
  } else {
    const unsigned* A = (const unsigned*)Av;
    #pragma unroll
    for (int ks = 0; ks < 4; ++ks) {
      uint4 u = *reinterpret_cast<const uint4*>(&A[(size_t)arow * 64 + ks * 16 + kb * 4]);
      if constexpr (RELU) {
        u.x = relu2(u.x); u.y = relu2(u.y); u.z = relu2(u.z); u.w = relu2(u.w);
      }
      afr[ks] = u;
    }
  }
  if (!valid) {
    afr[0] = make_uint4(0, 0, 0, 0); afr[1] = afr[0];
    afr[2] = afr[0];                 afr[3] = afr[0];
  }

  f32x4 acc[NT];
  #pragma unroll
  for (int nt = 0; nt < NT; ++nt) {
    acc[nt][0] = 0.f; acc[nt][1] = 0.f; acc[nt][2] = 0.f; acc[nt][3] = 0.f;
  }

  __syncthreads();
  #pragma unroll
  for (int ks = 0; ks < 4; ++ks) {
    const bf16x8 a = __builtin_bit_cast(bf16x8, afr[ks]);
    #pragma unroll
    for (int nt = 0; nt < NT; ++nt) {
      const uint4 bv = *reinterpret_cast<const uint4*>(&Ws[nt * 16 + am][ks * 32 + kb * 8]);
      acc[nt] = __builtin_amdgcn_mfma_f32_16x16x32_bf16(
          a, __builtin_bit_cast(bf16x8, bv), acc[nt], 0, 0, 0);
    }
  }

  // C/D layout: col = lane&15 (=am), row = 4*(lane>>4) (=kb*4) + reg.
  const int crow0 = blockIdx.x * 128 + wv * 16 + kb * 4;
  #pragma unroll
  for (int nt = 0; nt < NT; ++nt) {
    #pragma unroll
    for (int r = 0; r < 4; ++r) {
      const int rr = crow0 + r;
      if (rr < M) C[(size_t)rr * NOUT + nt * 16 + am] = f2bf(acc[nt][r]);
    }
  }
}

// ---------------------------------------------------------------------------
// Bin-grouped CSR build. bin = dst >> 9 (512 nodes/bin, <=256 bins).
// hist_k: per-(bin,block) counts, transposed layout histT[bin*256+blk].
// ---------------------------------------------------------------------------
__global__ __launch_bounds__(512) void hist_k(const int* __restrict__ dst,
                                              int* __restrict__ histT, int E) {
  __shared__ int h[256];
  if (threadIdx.x < 256) h[threadIdx.x] = 0;
  __syncthreads();
  for (int e = blockIdx.x * 512 + threadIdx.x; e < E; e += 256 * 512)
    atomicAdd(&h[dst[e] >> 9], 1);
  __syncthreads();
  if (threadIdx.x < 256) histT[threadIdx.x * 256 + blockIdx.x] = h[threadIdx.x];
}

// Block of 256 threads scans a 2048-int tile; block-local exclusive scan into
// out, tile total into bsum[blockIdx.x]. (N must allow int4 loads.)
__global__ __launch_bounds__(256) void scan1_k(const int* __restrict__ in,
                                               int* __restrict__ out,
                                               int* __restrict__ bsum, int N) {
  __shared__ int ls[256];
  const int t = threadIdx.x;
  const int base = blockIdx.x * 2048 + t * 8;
  int v[8];
  if (base + 8 <= N) {
    *reinterpret_cast<int4*>(&v[0]) = *reinterpret_cast<const int4*>(&in[base]);
    *reinterpret_cast<int4*>(&v[4]) = *reinterpret_cast<const int4*>(&in[base + 4]);
  } else {
    #pragma unroll
    for (int j = 0; j < 8; ++j) v[j] = (base + j < N) ? in[base + j] : 0;
  }
  int s = 0;
  #pragma unroll
  for (int j = 0; j < 8; ++j) { const int tmp = v[j]; v[j] = s; s += tmp; }
  int x = s;
  ls[t] = x;
  __syncthreads();
  for (int off = 1; off < 256; off <<= 1) {
    int y = 0;
    if (t >= off) y = ls[t - off];
    __syncthreads();
    x += y;
    ls[t] = x;
    __syncthreads();
  }
  const int excl = x - s;
  #pragma unroll
  for (int j = 0; j < 8; ++j)
    if (base + j < N) out[base + j] = excl + v[j];
  if (t == 255) bsum[blockIdx.x] = x;
}

__global__ __launch_bounds__(64) void scan2_k(const int* __restrict__ bsum,
                                              int* __restrict__ bscan, int NB) {
  const int t = threadIdx.x;
  const int v = (t < NB) ? bsum[t] : 0;
  int x = v;
  #pragma unroll
  for (int off = 1; off < 64; off <<= 1) {
    const int y = __shfl_up(x, off, 64);
    if (t >= off) x += y;
  }
  bscan[t] = x - v;
}

__global__ __launch_bounds__(256) void addoff_k(int* __restrict__ off,
                                                const int* __restrict__ bscan) {
  const int i = blockIdx.x * 256 + threadIdx.x;
  off[i] += bscan[i >> 11];
}

// binscatter: re-read same edge chunks, write packed (dst<<32|src) into
// bin-grouped epack via LDS cursors (256 sequential streams per block).
__global__ __launch_bounds__(512) void binscatter_k(const int* __restrict__ src,
                                                    const int* __restrict__ dst,
                                                    const int* __restrict__ histOff,
                                                    unsigned long long* __restrict__ epack,
                                                    int E) {
  __shared__ int cur[256];
  if (threadIdx.x < 256) cur[threadIdx.x] = histOff[threadIdx.x * 256 + blockIdx.x];
  __syncthreads();
  for (int e = blockIdx.x * 512 + threadIdx.x; e < E; e += 256 * 512) {
    const int d = dst[e], s = src[e];
    const int pos = atomicAdd(&cur[d >> 9], 1);
    epack[pos] = ((unsigned long long)(unsigned)d << 32) | (unsigned)s;
  }
}

// binsort: one block per bin. LDS 512-counter histogram + block scan ->
// rowptr for the bin's nodes; LDS-cursor scatter of src into col (hot window).
__global__ __launch_bounds__(512) void binsort_k(const unsigned long long* __restrict__ epack,
                                                 const int* __restrict__ histOff,
                                                 int* __restrict__ rowptr,
                                                 int* __restrict__ col,
                                                 int N, int E) {
  __shared__ int hist[512];
  __shared__ int ls[256];
  __shared__ int cur[512];
  const int b = blockIdx.x;
  const int t = threadIdx.x;
  const int nbins = (N + 511) >> 9;
  const int beg = histOff[b * 256];
  const int end = (b + 1 < nbins) ? histOff[(b + 1) * 256] : E;

  hist[t] = 0;
  __syncthreads();
  for (int j = beg + t; j < end; j += 512)
    atomicAdd(&hist[(int)(epack[j] >> 32) & 511], 1);
  __syncthreads();

  int a = 0, b2 = 0, x = 0;
  if (t < 256) { a = hist[2 * t]; b2 = hist[2 * t + 1]; x = a + b2; ls[t] = x; }
  __syncthreads();
  for (int off = 1; off < 256; off <<= 1) {
    int y = 0;
    if (t < 256 && t >= off) y = ls[t - off];
    __syncthreads();
    if (t < 256) { x += y; ls[t] = x; }
    __syncthreads();
  }
  if (t < 256) {
    const int excl = x - a - b2;          // exclusive prefix before elem 2t
    cur[2 * t] = excl;
    cur[2 * t + 1] = excl + a;
    const int g0 = b * 512 + 2 * t;
    if (g0 <= N) rowptr[g0] = beg + excl;
    if (g0 + 1 <= N) rowptr[g0 + 1] = beg + excl + a;
  }
  __syncthreads();
  for (int j = beg + t; j < end; j += 512) {
    const unsigned long long p = epack[j];
    const int d = (int)(p >> 32) & 511;
    const int s = (int)(p & 0xffffffffu);
    const int pos = atomicAdd(&cur[d], 1);
    col[beg + pos] = s;
  }
}

// ---------------------------------------------------------------------------
// Gather-aggregate, D=128 bf16 rows: one wave per dst node, lane holds 1 dword
// (2 bf16). Accumulate f32, write packed bf16 (feeds next MFMA GEMM).
// ---------------------------------------------------------------------------
__global__ __launch_bounds__(256) void gather128_k(const unsigned* __restrict__ Hu,
                                                   const int* __restrict__ rowptr,
                                                   const int* __restrict__ col,
                                                   unsigned* __restrict__ out, int N) {
  const int w = (int)((blockIdx.x * 256u + threadIdx.x) >> 6);
  const int lane = threadIdx.x & 63;
  if (w >= N) return;
  const int beg = rowptr[w];
  const int end = rowptr[w + 1];
  float2 a0 = make_float2(0.f, 0.f), a1 = make_float2(0.f, 0.f);
  float2 a2 = make_float2(0.f, 0.f), a3 = make_float2(0.f, 0.f);
  int e = beg;
  for (; e + 4 <= end; e += 4) {
    const int s0 = col[e],     s1 = col[e + 1];
    const int s2 = col[e + 2], s3 = col[e + 3];
    const unsigned u0 = Hu[(size_t)s0 * 64 + lane];
    const unsigned u1 = Hu[(size_t)s1 * 64 + lane];
    const unsigned u2 = Hu[(size_t)s2 * 64 + lane];
    const unsigned u3 = Hu[(size_t)s3 * 64 + lane];
    const float2 v0 = unpack_bf16x2(u0), v1 = unpack_bf16x2(u1);
    const float2 v2 = unpack_bf16x2(u2), v3 = unpack_bf16x2(u3);
    a0.x += v0.x; a0.y += v0.y;
    a1.x += v1.x; a1.y += v1.y;
    a2.x += v2.x; a2.y += v2.y;
    a3.x += v3.x; a3.y += v3.y;
  }
  for (; e < end; ++e) {
    const float2 v = unpack_bf16x2(Hu[(size_t)col[e] * 64 + lane]);
    a0.x += v.x; a0.y += v.y;
  }
  a0.x += a1.x + a2.x + a3.x;
  a0.y += a1.y + a2.y + a3.y;
  out[(size_t)w * 64 + lane] = pack_bf16x2(a0.x, a0.y);
}

// ---------------------------------------------------------------------------
// Gather-aggregate D=64 bf16 fused with row log_softmax: lane holds 1 value.
// ---------------------------------------------------------------------------
__global__ __launch_bounds__(256) void gather64lsm_k(const unsigned short* __restrict__ Hs,
                                                     const int* __restrict__ rowptr,
                                                     const int* __restrict__ col,
                                                     float* __restrict__ out, int N) {
  const int w = (int)((blockIdx.x * 256u + threadIdx.x) >> 6);
  const int lane = threadIdx.x & 63;
  if (w >= N) return;
  const int beg = rowptr[w];
  const int end = rowptr[w + 1];
  float a0 = 0.f, a1 = 0.f, a2 = 0.f, a3 = 0.f;
  int e = beg;
  for (; e + 4 <= end; e += 4) {
    a0 += bf2f(Hs[(size_t)col[e] * 64 + lane]);
    a1 += bf2f(Hs[(size_t)col[e + 1] * 64 + lane]);
    a2 += bf2f(Hs[(size_t)col[e + 2] * 64 + lane]);
    a3 += bf2f(Hs[(size_t)col[e + 3] * 64 + lane]);
  }
  for (; e < end; ++e) a0 += bf2f(Hs[(size_t)col[e] * 64 + lane]);
  const float v = (a0 + a1) + (a2 + a3);
  float m = v;
  #pragma unroll
  for (int o = 32; o > 0; o >>= 1) m = fmaxf(m, __shfl_xor(m, o, 64));
  const float ex = __expf(v - m);
  float s = ex;
  #pragma unroll
  for (int o = 32; o > 0; o >>= 1) s += __shfl_xor(s, o, 64);
  out[(size_t)w * 64 + lane] = v - m - __logf(s);
}

extern "C" void kernel_launch(void* const* d_in, const int* in_sizes, int n_in,
                              void* d_out, int out_size, void* d_ws, size_t ws_size,
                              hipStream_t stream) {
  const float* x  = (const float*)d_in[0];
  const int*   ei = (const int*)d_in[1];
  const float* W1 = (const float*)d_in[2];
  const float* W2 = (const float*)d_in[3];
  const float* W3 = (const float*)d_in[4];
  float* out = (float*)d_out;

  const int N = in_sizes[0] / KDIM;       // 100000
  const int E = in_sizes[1] / 2;          // 1600000
  const int* src = ei;
  const int* dst = ei + E;

  // Workspace layout (all chunks 16B-aligned)
  unsigned short* H = (unsigned short*)d_ws;            // [N,128] bf16
  unsigned* AGGp = (unsigned*)(H + (size_t)N * KDIM);   // [N,64] packed bf16 pairs
  unsigned short* Wt1 = (unsigned short*)(AGGp + (size_t)N * 64);  // [128,128]
  unsigned short* Wt2 = Wt1 + 128 * 128;                // [128,128]
  unsigned short* Wt3 = Wt2 + 128 * 128;                // [64,128]
  int* col     = (int*)(Wt3 + 64 * 128);                // [E]
  int* rowptr  = col + E;                               // [N+8]
  int* histT   = rowptr + (N + 8);                      // [65536]
  int* histOff = histT + 65536;                         // [65536]
  int* bsum2   = histOff + 65536;                       // [64]
  int* bscan2  = bsum2 + 64;                            // [64]
  // epack aliases AGGp (dead until layer-1 gather): E*8B <= N*64*4B
  unsigned long long* epack = (unsigned long long*)AGGp;

  const int nbins = (N + 511) / 512;                    // 196

  // ---- W transposes (tiny, once) ----
  wtrans_k<<<(128 * 128 + 255) / 256, 256, 0, stream>>>(W1, Wt1, 128);
  wtrans_k<<<(128 * 128 + 255) / 256, 256, 0, stream>>>(W2, Wt2, 128);
  wtrans_k<<<(64 * 128 + 255) / 256, 256, 0, stream>>>(W3, Wt3, 64);

  // ---- CSR build: bin histogram -> scan -> bin scatter -> per-bin sort ----
  hist_k<<<256, 512, 0, stream>>>(dst, histT, E);
  scan1_k<<<32, 256, 0, stream>>>(histT, histOff, bsum2, 65536);
  scan2_k<<<1, 64, 0, stream>>>(bsum2, bscan2, 32);
  addoff_k<<<256, 256, 0, stream>>>(histOff, bscan2);
  binscatter_k<<<256, 512, 0, stream>>>(src, dst, histOff, epack, E);
  binsort_k<<<nbins, 512, 0, stream>>>(epack, histOff, rowptr, col, N, E);

  const int gemm_grid = (N + 127) / 128;
  const int gather_grid = (N + 3) / 4;

  // ---- layer 1 ----
  gemm_mfma_k<128, true, false><<<gemm_grid, 512, 0, stream>>>(x, Wt1, H, N);
  gather128_k<<<gather_grid, 256, 0, stream>>>((const unsigned*)H, rowptr, col, AGGp, N);

  // ---- layer 2 ----
  gemm_mfma_k<128, false, true><<<gemm_grid, 512, 0, stream>>>(AGGp, Wt2, H, N);
  gather128_k<<<gather_grid, 256, 0, stream>>>((const unsigned*)H, rowptr, col, AGGp, N);

  // ---- layer 3 (+ fused log_softmax) ----
  gemm_mfma_k<64, false, true><<<gemm_grid, 512, 0, stream>>>(AGGp, Wt3, H, N);
  gather64lsm_k<<<gather_grid, 256, 0, stream>>>((const unsigned short*)H, rowptr, col, out, N);
}

// Round 7
// 266.585 us; speedup vs baseline: 25.9442x; 1.1120x over previous
//
#include <hip/hip_runtime.h>
#include <hip/hip_bf16.h>

#define KDIM 128

typedef __attribute__((ext_vector_type(8))) __bf16 bf16x8;
typedef __attribute__((ext_vector_type(4))) float f32x4;

// bf16 pack/unpack via explicit bit ops (ROCm header API names vary).
static __device__ __forceinline__ unsigned short f2bf(float f) {
  unsigned u = __float_as_uint(f);
  u += 0x7fffu + ((u >> 16) & 1u);        // round-to-nearest-even
  return (unsigned short)(u >> 16);
}
static __device__ __forceinline__ unsigned pack_bf16x2(float a, float b) {
  return (unsigned)f2bf(a) | ((unsigned)f2bf(b) << 16);
}
static __device__ __forceinline__ float bf2f(unsigned short s) {
  return __uint_as_float((unsigned)s << 16);
}
static __device__ __forceinline__ float2 unpack_bf16x2(unsigned u) {
  return make_float2(__uint_as_float(u << 16), __uint_as_float(u & 0xffff0000u));
}
// ReLU on a packed pair of bf16 (zero any half with sign bit set).
static __device__ __forceinline__ unsigned relu2(unsigned u) {
  unsigned r = u;
  if (u & 0x00008000u) r &= 0xffff0000u;
  if (u & 0x80000000u) r &= 0x0000ffffu;
  return r;
}

// ---------------------------------------------------------------------------
// W transpose + bf16 cast: Wt[n][k] = bf16(W[k][n]). K=128 fixed.
// ---------------------------------------------------------------------------
__global__ __launch_bounds__(256) void wtrans_k(const float* __restrict__ W,
                                                unsigned short* __restrict__ Wt,
                                                int NOUT) {
  const int t = blockIdx.x * 256 + threadIdx.x;
  if (t >= NOUT * KDIM) return;
  const int n = t >> 7;                   // t / 128
  const int k = t & 127;                  // t % 128
  Wt[t] = f2bf(W[k * NOUT + n]);
}

// ---------------------------------------------------------------------------
// MFMA GEMM: C[M,NOUT](bf16) = act(A[M,128]) @ W, W given as Wt[n][k] bf16.
// Block: 512 threads = 8 waves, BM=128 (16 rows/wave). mfma_f32_16x16x32_bf16.
// ---------------------------------------------------------------------------
template<int NOUT, bool AF32, bool RELU>
__global__ __launch_bounds__(512) void gemm_mfma_k(const void* __restrict__ Av,
                                                   const unsigned short* __restrict__ Wt,
                                                   unsigned short* __restrict__ C, int M) {
  constexpr int NT = NOUT / 16;           // n-tiles per wave
  __shared__ unsigned short Ws[NOUT][136];  // [n][k], +8 pad breaks conflicts

  const int tid = threadIdx.x;
  for (int i = tid; i < NOUT * 16; i += 512) {
    const int n = i >> 4, k8 = i & 15;
    const uint4 v = *reinterpret_cast<const uint4*>(&Wt[n * KDIM + k8 * 8]);
    *reinterpret_cast<uint4*>(&Ws[n][k8 * 8]) = v;
  }

  const int wv = tid >> 6;                // wave 0..7
  const int l  = tid & 63;
  const int am = l & 15;                  // A row within 16-row tile / C col
  const int kb = l >> 4;                  // k-block 0..3
  const int arow_g = blockIdx.x * 128 + wv * 16 + am;
  const bool valid = arow_g < M;
  const int arow = valid ? arow_g : 0;

  uint4 afr[4];
  if constexpr (AF32) {
    const float* A = (const float*)Av;
    #pragma unroll
    for (int ks = 0; ks < 4; ++ks) {
      const float4 lo = *reinterpret_cast<const float4*>(&A[(size_t)arow * 128 + ks * 32 + kb * 8]);
      const float4 hi = *reinterpret_cast<const float4*>(&A[(size_t)arow * 128 + ks * 32 + kb * 8 + 4]);
      afr[ks] = make_uint4(pack_bf16x2(lo.x, lo.y), pack_bf16x2(lo.z, lo.w),
                           pack_bf16x2(hi.x, hi.y), pack_bf16x2(hi.z, hi.w));
    }
  } else {
    const unsigned* A = (const unsigned*)Av;
    #pragma unroll
    for (int ks = 0; ks < 4; ++ks) {
      uint4 u = *reinterpret_cast<const uint4*>(&A[(size_t)arow * 64 + ks * 16 + kb * 4]);
      if constexpr (RELU) {
        u.x = relu2(u.x); u.y = relu2(u.y); u.z = relu2(u.z); u.w = relu2(u.w);
      }
      afr[ks] = u;
    }
  }
  if (!valid) {
    afr[0] = make_uint4(0, 0, 0, 0); afr[1] = afr[0];
    afr[2] = afr[0];                 afr[3] = afr[0];
  }

  f32x4 acc[NT];
  #pragma unroll
  for (int nt = 0; nt < NT; ++nt) {
    acc[nt][0] = 0.f; acc[nt][1] = 0.f; acc[nt][2] = 0.f; acc[nt][3] = 0.f;
  }

  __syncthreads();
  #pragma unroll
  for (int ks = 0; ks < 4; ++ks) {
    const bf16x8 a = __builtin_bit_cast(bf16x8, afr[ks]);
    #pragma unroll
    for (int nt = 0; nt < NT; ++nt) {
      const uint4 bv = *reinterpret_cast<const uint4*>(&Ws[nt * 16 + am][ks * 32 + kb * 8]);
      acc[nt] = __builtin_amdgcn_mfma_f32_16x16x32_bf16(
          a, __builtin_bit_cast(bf16x8, bv), acc[nt], 0, 0, 0);
    }
  }

  // C/D layout: col = lane&15 (=am), row = 4*(lane>>4) (=kb*4) + reg.
  const int crow0 = blockIdx.x * 128 + wv * 16 + kb * 4;
  #pragma unroll
  for (int nt = 0; nt < NT; ++nt) {
    #pragma unroll
    for (int r = 0; r < 4; ++r) {
      const int rr = crow0 + r;
      if (rr < M) C[(size_t)rr * NOUT + nt * 16 + am] = f2bf(acc[nt][r]);
    }
  }
}

// ---------------------------------------------------------------------------
// Bin-grouped CSR build. bin = dst >> 9 (512 nodes/bin, <=256 bins).
// ---------------------------------------------------------------------------
__global__ __launch_bounds__(512) void hist_k(const int* __restrict__ dst,
                                              int* __restrict__ histT, int E) {
  __shared__ int h[256];
  if (threadIdx.x < 256) h[threadIdx.x] = 0;
  __syncthreads();
  for (int e = blockIdx.x * 512 + threadIdx.x; e < E; e += 256 * 512)
    atomicAdd(&h[dst[e] >> 9], 1);
  __syncthreads();
  if (threadIdx.x < 256) histT[threadIdx.x * 256 + blockIdx.x] = h[threadIdx.x];
}

__global__ __launch_bounds__(256) void scan1_k(const int* __restrict__ in,
                                               int* __restrict__ out,
                                               int* __restrict__ bsum, int N) {
  __shared__ int ls[256];
  const int t = threadIdx.x;
  const int base = blockIdx.x * 2048 + t * 8;
  int v[8];
  if (base + 8 <= N) {
    *reinterpret_cast<int4*>(&v[0]) = *reinterpret_cast<const int4*>(&in[base]);
    *reinterpret_cast<int4*>(&v[4]) = *reinterpret_cast<const int4*>(&in[base + 4]);
  } else {
    #pragma unroll
    for (int j = 0; j < 8; ++j) v[j] = (base + j < N) ? in[base + j] : 0;
  }
  int s = 0;
  #pragma unroll
  for (int j = 0; j < 8; ++j) { const int tmp = v[j]; v[j] = s; s += tmp; }
  int x = s;
  ls[t] = x;
  __syncthreads();
  for (int off = 1; off < 256; off <<= 1) {
    int y = 0;
    if (t >= off) y = ls[t - off];
    __syncthreads();
    x += y;
    ls[t] = x;
    __syncthreads();
  }
  const int excl = x - s;
  #pragma unroll
  for (int j = 0; j < 8; ++j)
    if (base + j < N) out[base + j] = excl + v[j];
  if (t == 255) bsum[blockIdx.x] = x;
}

__global__ __launch_bounds__(64) void scan2_k(const int* __restrict__ bsum,
                                              int* __restrict__ bscan, int NB) {
  const int t = threadIdx.x;
  const int v = (t < NB) ? bsum[t] : 0;
  int x = v;
  #pragma unroll
  for (int off = 1; off < 64; off <<= 1) {
    const int y = __shfl_up(x, off, 64);
    if (t >= off) x += y;
  }
  bscan[t] = x - v;
}

__global__ __launch_bounds__(256) void addoff_k(int* __restrict__ off,
                                                const int* __restrict__ bscan) {
  const int i = blockIdx.x * 256 + threadIdx.x;
  off[i] += bscan[i >> 11];
}

__global__ __launch_bounds__(512) void binscatter_k(const int* __restrict__ src,
                                                    const int* __restrict__ dst,
                                                    const int* __restrict__ histOff,
                                                    unsigned long long* __restrict__ epack,
                                                    int E) {
  __shared__ int cur[256];
  if (threadIdx.x < 256) cur[threadIdx.x] = histOff[threadIdx.x * 256 + blockIdx.x];
  __syncthreads();
  for (int e = blockIdx.x * 512 + threadIdx.x; e < E; e += 256 * 512) {
    const int d = dst[e], s = src[e];
    const int pos = atomicAdd(&cur[d >> 9], 1);
    epack[pos] = ((unsigned long long)(unsigned)d << 32) | (unsigned)s;
  }
}

__global__ __launch_bounds__(512) void binsort_k(const unsigned long long* __restrict__ epack,
                                                 const int* __restrict__ histOff,
                                                 int* __restrict__ rowptr,
                                                 int* __restrict__ col,
                                                 int N, int E) {
  __shared__ int hist[512];
  __shared__ int ls[256];
  __shared__ int cur[512];
  const int b = blockIdx.x;
  const int t = threadIdx.x;
  const int nbins = (N + 511) >> 9;
  const int beg = histOff[b * 256];
  const int end = (b + 1 < nbins) ? histOff[(b + 1) * 256] : E;

  hist[t] = 0;
  __syncthreads();
  for (int j = beg + t; j < end; j += 512)
    atomicAdd(&hist[(int)(epack[j] >> 32) & 511], 1);
  __syncthreads();

  int a = 0, b2 = 0, x = 0;
  if (t < 256) { a = hist[2 * t]; b2 = hist[2 * t + 1]; x = a + b2; ls[t] = x; }
  __syncthreads();
  for (int off = 1; off < 256; off <<= 1) {
    int y = 0;
    if (t < 256 && t >= off) y = ls[t - off];
    __syncthreads();
    if (t < 256) { x += y; ls[t] = x; }
    __syncthreads();
  }
  if (t < 256) {
    const int excl = x - a - b2;
    cur[2 * t] = excl;
    cur[2 * t + 1] = excl + a;
    const int g0 = b * 512 + 2 * t;
    if (g0 <= N) rowptr[g0] = beg + excl;
    if (g0 + 1 <= N) rowptr[g0 + 1] = beg + excl + a;
  }
  __syncthreads();
  for (int j = beg + t; j < end; j += 512) {
    const unsigned long long p = epack[j];
    const int d = (int)(p >> 32) & 511;
    const int s = (int)(p & 0xffffffffu);
    const int pos = atomicAdd(&cur[d], 1);
    col[beg + pos] = s;
  }
}

// ---------------------------------------------------------------------------
// Gather-aggregate, D=128 bf16 rows. One wave per dst node; lanes 0-31 handle
// even edges, lanes 32-63 odd edges; each lane loads uint2 (4 bf16) so a
// half-wave covers a full 256B row. Cross-half combine via shfl_xor(32).
// ---------------------------------------------------------------------------
__global__ __launch_bounds__(256) void gather128_k(const unsigned* __restrict__ Hu,
                                                   const int* __restrict__ rowptr,
                                                   const int* __restrict__ col,
                                                   unsigned* __restrict__ out, int N) {
  const int w = (int)((blockIdx.x * 256u + threadIdx.x) >> 6);
  const int lane = threadIdx.x & 63;
  const int h = lane >> 5;                // half 0/1
  const int l5 = lane & 31;
  if (w >= N) return;
  const int beg = __builtin_amdgcn_readfirstlane(rowptr[w]);
  const int end = __builtin_amdgcn_readfirstlane(rowptr[w + 1]);

  float4 acc0 = make_float4(0.f, 0.f, 0.f, 0.f);
  float4 acc1 = make_float4(0.f, 0.f, 0.f, 0.f);
  float4 acc2 = make_float4(0.f, 0.f, 0.f, 0.f);
  float4 acc3 = make_float4(0.f, 0.f, 0.f, 0.f);

  int e = beg;
  for (; e + 8 <= end; e += 8) {
    const int sA = col[e + h];
    const int sB = col[e + 2 + h];
    const int sC = col[e + 4 + h];
    const int sD = col[e + 6 + h];
    const uint2 uA = *reinterpret_cast<const uint2*>(&Hu[(size_t)sA * 64 + l5 * 2]);
    const uint2 uB = *reinterpret_cast<const uint2*>(&Hu[(size_t)sB * 64 + l5 * 2]);
    const uint2 uC = *reinterpret_cast<const uint2*>(&Hu[(size_t)sC * 64 + l5 * 2]);
    const uint2 uD = *reinterpret_cast<const uint2*>(&Hu[(size_t)sD * 64 + l5 * 2]);
    float2 p, q;
    p = unpack_bf16x2(uA.x); q = unpack_bf16x2(uA.y);
    acc0.x += p.x; acc0.y += p.y; acc0.z += q.x; acc0.w += q.y;
    p = unpack_bf16x2(uB.x); q = unpack_bf16x2(uB.y);
    acc1.x += p.x; acc1.y += p.y; acc1.z += q.x; acc1.w += q.y;
    p = unpack_bf16x2(uC.x); q = unpack_bf16x2(uC.y);
    acc2.x += p.x; acc2.y += p.y; acc2.z += q.x; acc2.w += q.y;
    p = unpack_bf16x2(uD.x); q = unpack_bf16x2(uD.y);
    acc3.x += p.x; acc3.y += p.y; acc3.z += q.x; acc3.w += q.y;
  }
  for (; e + 2 <= end; e += 2) {
    const int s = col[e + h];
    const uint2 u = *reinterpret_cast<const uint2*>(&Hu[(size_t)s * 64 + l5 * 2]);
    const float2 p = unpack_bf16x2(u.x), q = unpack_bf16x2(u.y);
    acc0.x += p.x; acc0.y += p.y; acc0.z += q.x; acc0.w += q.y;
  }
  if (e < end && h == 0) {                // last odd edge: half 0 only
    const int s = col[e];
    const uint2 u = *reinterpret_cast<const uint2*>(&Hu[(size_t)s * 64 + l5 * 2]);
    const float2 p = unpack_bf16x2(u.x), q = unpack_bf16x2(u.y);
    acc1.x += p.x; acc1.y += p.y; acc1.z += q.x; acc1.w += q.y;
  }

  float4 a;
  a.x = (acc0.x + acc1.x) + (acc2.x + acc3.x);
  a.y = (acc0.y + acc1.y) + (acc2.y + acc3.y);
  a.z = (acc0.z + acc1.z) + (acc2.z + acc3.z);
  a.w = (acc0.w + acc1.w) + (acc2.w + acc3.w);
  a.x += __shfl_xor(a.x, 32, 64);
  a.y += __shfl_xor(a.y, 32, 64);
  a.z += __shfl_xor(a.z, 32, 64);
  a.w += __shfl_xor(a.w, 32, 64);

  if (h == 0) {
    *reinterpret_cast<uint2*>(&out[(size_t)w * 64 + l5 * 2]) =
        make_uint2(pack_bf16x2(a.x, a.y), pack_bf16x2(a.z, a.w));
  }
}

// ---------------------------------------------------------------------------
// Gather-aggregate D=64 bf16 + fused log_softmax. Same half-wave scheme:
// lane loads 1 dword (2 bf16); half-wave covers the 128B row.
// ---------------------------------------------------------------------------
__global__ __launch_bounds__(256) void gather64lsm_k(const unsigned* __restrict__ Hu,
                                                     const int* __restrict__ rowptr,
                                                     const int* __restrict__ col,
                                                     float* __restrict__ out, int N) {
  const int w = (int)((blockIdx.x * 256u + threadIdx.x) >> 6);
  const int lane = threadIdx.x & 63;
  const int h = lane >> 5;
  const int l5 = lane & 31;
  if (w >= N) return;
  const int beg = __builtin_amdgcn_readfirstlane(rowptr[w]);
  const int end = __builtin_amdgcn_readfirstlane(rowptr[w + 1]);

  float2 acc0 = make_float2(0.f, 0.f), acc1 = make_float2(0.f, 0.f);
  float2 acc2 = make_float2(0.f, 0.f), acc3 = make_float2(0.f, 0.f);

  int e = beg;
  for (; e + 8 <= end; e += 8) {
    const int sA = col[e + h];
    const int sB = col[e + 2 + h];
    const int sC = col[e + 4 + h];
    const int sD = col[e + 6 + h];
    const unsigned uA = Hu[(size_t)sA * 32 + l5];
    const unsigned uB = Hu[(size_t)sB * 32 + l5];
    const unsigned uC = Hu[(size_t)sC * 32 + l5];
    const unsigned uD = Hu[(size_t)sD * 32 + l5];
    float2 p;
    p = unpack_bf16x2(uA); acc0.x += p.x; acc0.y += p.y;
    p = unpack_bf16x2(uB); acc1.x += p.x; acc1.y += p.y;
    p = unpack_bf16x2(uC); acc2.x += p.x; acc2.y += p.y;
    p = unpack_bf16x2(uD); acc3.x += p.x; acc3.y += p.y;
  }
  for (; e + 2 <= end; e += 2) {
    const unsigned u = Hu[(size_t)col[e + h] * 32 + l5];
    const float2 p = unpack_bf16x2(u);
    acc0.x += p.x; acc0.y += p.y;
  }
  if (e < end && h == 0) {
    const unsigned u = Hu[(size_t)col[e] * 32 + l5];
    const float2 p = unpack_bf16x2(u);
    acc1.x += p.x; acc1.y += p.y;
  }

  float vx = (acc0.x + acc1.x) + (acc2.x + acc3.x);
  float vy = (acc0.y + acc1.y) + (acc2.y + acc3.y);
  vx += __shfl_xor(vx, 32, 64);
  vy += __shfl_xor(vy, 32, 64);

  // halves now duplicate; reduce within 32-lane halves.
  float m = fmaxf(vx, vy);
  #pragma unroll
  for (int o = 16; o > 0; o >>= 1) m = fmaxf(m, __shfl_xor(m, o, 64));
  float s = __expf(vx - m) + __expf(vy - m);
  #pragma unroll
  for (int o = 16; o > 0; o >>= 1) s += __shfl_xor(s, o, 64);
  const float ls = __logf(s);

  if (h == 0) {
    *reinterpret_cast<float2*>(&out[(size_t)w * 64 + l5 * 2]) =
        make_float2(vx - m - ls, vy - m - ls);
  }
}

extern "C" void kernel_launch(void* const* d_in, const int* in_sizes, int n_in,
                              void* d_out, int out_size, void* d_ws, size_t ws_size,
                              hipStream_t stream) {
  const float* x  = (const float*)d_in[0];
  const int*   ei = (const int*)d_in[1];
  const float* W1 = (const float*)d_in[2];
  const float* W2 = (const float*)d_in[3];
  const float* W3 = (const float*)d_in[4];
  float* out = (float*)d_out;

  const int N = in_sizes[0] / KDIM;       // 100000
  const int E = in_sizes[1] / 2;          // 1600000
  const int* src = ei;
  const int* dst = ei + E;

  // Workspace layout (all chunks 16B-aligned)
  unsigned short* H = (unsigned short*)d_ws;            // [N,128] bf16
  unsigned* AGGp = (unsigned*)(H + (size_t)N * KDIM);   // [N,64] packed bf16 pairs
  unsigned short* Wt1 = (unsigned short*)(AGGp + (size_t)N * 64);  // [128,128]
  unsigned short* Wt2 = Wt1 + 128 * 128;                // [128,128]
  unsigned short* Wt3 = Wt2 + 128 * 128;                // [64,128]
  int* col     = (int*)(Wt3 + 64 * 128);                // [E]
  int* rowptr  = col + E;                               // [N+8]
  int* histT   = rowptr + (N + 8);                      // [65536]
  int* histOff = histT + 65536;                         // [65536]
  int* bsum2   = histOff + 65536;                       // [64]
  int* bscan2  = bsum2 + 64;                            // [64]
  // epack aliases AGGp (dead until layer-1 gather): E*8B <= N*64*4B
  unsigned long long* epack = (unsigned long long*)AGGp;

  const int nbins = (N + 511) / 512;                    // 196

  // ---- W transposes (tiny, once) ----
  wtrans_k<<<(128 * 128 + 255) / 256, 256, 0, stream>>>(W1, Wt1, 128);
  wtrans_k<<<(128 * 128 + 255) / 256, 256, 0, stream>>>(W2, Wt2, 128);
  wtrans_k<<<(64 * 128 + 255) / 256, 256, 0, stream>>>(W3, Wt3, 64);

  // ---- CSR build: bin histogram -> scan -> bin scatter -> per-bin sort ----
  hist_k<<<256, 512, 0, stream>>>(dst, histT, E);
  scan1_k<<<32, 256, 0, stream>>>(histT, histOff, bsum2, 65536);
  scan2_k<<<1, 64, 0, stream>>>(bsum2, bscan2, 32);
  addoff_k<<<256, 256, 0, stream>>>(histOff, bscan2);
  binscatter_k<<<256, 512, 0, stream>>>(src, dst, histOff, epack, E);
  binsort_k<<<nbins, 512, 0, stream>>>(epack, histOff, rowptr, col, N, E);

  const int gemm_grid = (N + 127) / 128;
  const int gather_grid = (N + 3) / 4;

  // ---- layer 1 ----
  gemm_mfma_k<128, true, false><<<gemm_grid, 512, 0, stream>>>(x, Wt1, H, N);
  gather128_k<<<gather_grid, 256, 0, stream>>>((const unsigned*)H, rowptr, col, AGGp, N);

  // ---- layer 2 ----
  gemm_mfma_k<128, false, true><<<gemm_grid, 512, 0, stream>>>(AGGp, Wt2, H, N);
  gather128_k<<<gather_grid, 256, 0, stream>>>((const unsigned*)H, rowptr, col, AGGp, N);

  // ---- layer 3 (+ fused log_softmax) ----
  gemm_mfma_k<64, false, true><<<gemm_grid, 512, 0, stream>>>(AGGp, Wt3, H, N);
  gather64lsm_k<<<gather_grid, 256, 0, stream>>>((const unsigned*)H, rowptr, col, out, N);
}

// Round 8
// 232.706 us; speedup vs baseline: 29.7213x; 1.1456x over previous
//
#include <hip/hip_runtime.h>
#include <hip/hip_bf16.h>

#define KDIM 128

typedef __attribute__((ext_vector_type(8))) __bf16 bf16x8;
typedef __attribute__((ext_vector_type(4))) float f32x4;
typedef __attribute__((ext_vector_type(2))) float f32x2;

// bf16 pack/unpack via explicit bit ops.
static __device__ __forceinline__ unsigned short f2bf(float f) {
  unsigned u = __float_as_uint(f);
  u += 0x7fffu + ((u >> 16) & 1u);        // round-to-nearest-even
  return (unsigned short)(u >> 16);
}
static __device__ __forceinline__ unsigned pack_bf16x2(float a, float b) {
  return (unsigned)f2bf(a) | ((unsigned)f2bf(b) << 16);
}
static __device__ __forceinline__ float2 unpack_bf16x2(unsigned u) {
  return make_float2(__uint_as_float(u << 16), __uint_as_float(u & 0xffff0000u));
}
// ReLU on a packed pair of bf16.
static __device__ __forceinline__ unsigned relu2(unsigned u) {
  unsigned r = u;
  if (u & 0x00008000u) r &= 0xffff0000u;
  if (u & 0x80000000u) r &= 0x0000ffffu;
  return r;
}

// ---------------------------------------------------------------------------
// fp8 (OCP e4m3fn) encode/decode. HW cvt if available, software fallback.
// ---------------------------------------------------------------------------
static __device__ __forceinline__ unsigned char f2fp8(float f) {
#if __has_builtin(__builtin_amdgcn_cvt_pk_fp8_f32)
  return (unsigned char)(__builtin_amdgcn_cvt_pk_fp8_f32(f, f, 0, false) & 0xff);
#else
  unsigned s = (__float_as_uint(f) >> 24) & 0x80u;
  float a = fminf(fabsf(f), 448.f);
  if (a < 0.015625f) {                     // subnormal: round a/2^-9
    unsigned m = (unsigned)(a * 512.f + 0.5f);
    return (unsigned char)(s | m);
  }
  unsigned v = __float_as_uint(a);
  v += 0x7ffffu + ((v >> 20) & 1u);        // RNE into 3-bit mantissa
  unsigned em = (v >> 20) - 960u;
  if (em > 0x7eu) em = 0x7eu;
  return (unsigned char)(s | em);
#endif
}
static __device__ __forceinline__ float fp8dec(unsigned b) {
  unsigned s = (b & 0x80u) << 24;
  unsigned em = b & 0x7fu;
  float mag = (em >= 8) ? __uint_as_float((em + 960u) << 20)
                        : (float)em * 0.001953125f;   // em * 2^-9
  return __uint_as_float(__float_as_uint(mag) | s);
}
static __device__ __forceinline__ float4 fp8x4_to_f32(unsigned u) {
#if __has_builtin(__builtin_amdgcn_cvt_pk_f32_fp8)
  f32x2 lo = __builtin_amdgcn_cvt_pk_f32_fp8(u, false);
  f32x2 hi = __builtin_amdgcn_cvt_pk_f32_fp8(u, true);
  return make_float4(lo[0], lo[1], hi[0], hi[1]);
#else
  return make_float4(fp8dec(u & 255u), fp8dec((u >> 8) & 255u),
                     fp8dec((u >> 16) & 255u), fp8dec(u >> 24));
#endif
}

// ---------------------------------------------------------------------------
// W transpose + bf16 cast: Wt[n][k] = bf16(W[k][n]). K=128 fixed.
// ---------------------------------------------------------------------------
__global__ __launch_bounds__(256) void wtrans_k(const float* __restrict__ W,
                                                unsigned short* __restrict__ Wt,
                                                int NOUT) {
  const int t = blockIdx.x * 256 + threadIdx.x;
  if (t >= NOUT * KDIM) return;
  const int n = t >> 7;
  const int k = t & 127;
  Wt[t] = f2bf(W[k * NOUT + n]);
}

// ---------------------------------------------------------------------------
// MFMA GEMM: C[M,NOUT](fp8) = act(A[M,128]) @ W, W given as Wt[n][k] bf16.
// Block: 512 threads = 8 waves, BM=128 (16 rows/wave). mfma_f32_16x16x32_bf16.
// ---------------------------------------------------------------------------
template<int NOUT, bool AF32, bool RELU>
__global__ __launch_bounds__(512) void gemm_mfma_k(const void* __restrict__ Av,
                                                   const unsigned short* __restrict__ Wt,
                                                   unsigned char* __restrict__ C, int M) {
  constexpr int NT = NOUT / 16;           // n-tiles per wave
  __shared__ unsigned short Ws[NOUT][136];

  const int tid = threadIdx.x;
  for (int i = tid; i < NOUT * 16; i += 512) {
    const int n = i >> 4, k8 = i & 15;
    const uint4 v = *reinterpret_cast<const uint4*>(&Wt[n * KDIM + k8 * 8]);
    *reinterpret_cast<uint4*>(&Ws[n][k8 * 8]) = v;
  }

  const int wv = tid >> 6;
  const int l  = tid & 63;
  const int am = l & 15;
  const int kb = l >> 4;
  const int arow_g = blockIdx.x * 128 + wv * 16 + am;
  const bool valid = arow_g < M;
  const int arow = valid ? arow_g : 0;

  uint4 afr[4];
  if constexpr (AF32) {
    const float* A = (const float*)Av;
    #pragma unroll
    for (int ks = 0; ks < 4; ++ks) {
      const float4 lo = *reinterpret_cast<const float4*>(&A[(size_t)arow * 128 + ks * 32 + kb * 8]);
      const float4 hi = *reinterpret_cast<const float4*>(&A[(size_t)arow * 128 + ks * 32 + kb * 8 + 4]);
      afr[ks] = make_uint4(pack_bf16x2(lo.x, lo.y), pack_bf16x2(lo.z, lo.w),
                           pack_bf16x2(hi.x, hi.y), pack_bf16x2(hi.z, hi.w));
    }
  } else {
    const unsigned* A = (const unsigned*)Av;
    #pragma unroll
    for (int ks = 0; ks < 4; ++ks) {
      uint4 u = *reinterpret_cast<const uint4*>(&A[(size_t)arow * 64 + ks * 16 + kb * 4]);
      if constexpr (RELU) {
        u.x = relu2(u.x); u.y = relu2(u.y); u.z = relu2(u.z); u.w = relu2(u.w);
      }
      afr[ks] = u;
    }
  }
  if (!valid) {
    afr[0] = make_uint4(0, 0, 0, 0); afr[1] = afr[0];
    afr[2] = afr[0];                 afr[3] = afr[0];
  }

  f32x4 acc[NT];
  #pragma unroll
  for (int nt = 0; nt < NT; ++nt) {
    acc[nt][0] = 0.f; acc[nt][1] = 0.f; acc[nt][2] = 0.f; acc[nt][3] = 0.f;
  }

  __syncthreads();
  #pragma unroll
  for (int ks = 0; ks < 4; ++ks) {
    const bf16x8 a = __builtin_bit_cast(bf16x8, afr[ks]);
    #pragma unroll
    for (int nt = 0; nt < NT; ++nt) {
      const uint4 bv = *reinterpret_cast<const uint4*>(&Ws[nt * 16 + am][ks * 32 + kb * 8]);
      acc[nt] = __builtin_amdgcn_mfma_f32_16x16x32_bf16(
          a, __builtin_bit_cast(bf16x8, bv), acc[nt], 0, 0, 0);
    }
  }

  // C/D layout: col = lane&15 (=am), row = 4*(lane>>4) (=kb*4) + reg.
  const int crow0 = blockIdx.x * 128 + wv * 16 + kb * 4;
  #pragma unroll
  for (int nt = 0; nt < NT; ++nt) {
    #pragma unroll
    for (int r = 0; r < 4; ++r) {
      const int rr = crow0 + r;
      if (rr < M) C[(size_t)rr * NOUT + nt * 16 + am] = f2fp8(acc[nt][r]);
    }
  }
}

// ---------------------------------------------------------------------------
// Bin-grouped CSR build. bin = dst >> 9 (512 nodes/bin, <=256 bins).
// ---------------------------------------------------------------------------
__global__ __launch_bounds__(512) void hist_k(const int* __restrict__ dst,
                                              int* __restrict__ histT, int E) {
  __shared__ int h[256];
  if (threadIdx.x < 256) h[threadIdx.x] = 0;
  __syncthreads();
  for (int e = blockIdx.x * 512 + threadIdx.x; e < E; e += 256 * 512)
    atomicAdd(&h[dst[e] >> 9], 1);
  __syncthreads();
  if (threadIdx.x < 256) histT[threadIdx.x * 256 + blockIdx.x] = h[threadIdx.x];
}

__global__ __launch_bounds__(256) void scan1_k(const int* __restrict__ in,
                                               int* __restrict__ out,
                                               int* __restrict__ bsum, int N) {
  __shared__ int ls[256];
  const int t = threadIdx.x;
  const int base = blockIdx.x * 2048 + t * 8;
  int v[8];
  if (base + 8 <= N) {
    *reinterpret_cast<int4*>(&v[0]) = *reinterpret_cast<const int4*>(&in[base]);
    *reinterpret_cast<int4*>(&v[4]) = *reinterpret_cast<const int4*>(&in[base + 4]);
  } else {
    #pragma unroll
    for (int j = 0; j < 8; ++j) v[j] = (base + j < N) ? in[base + j] : 0;
  }
  int s = 0;
  #pragma unroll
  for (int j = 0; j < 8; ++j) { const int tmp = v[j]; v[j] = s; s += tmp; }
  int x = s;
  ls[t] = x;
  __syncthreads();
  for (int off = 1; off < 256; off <<= 1) {
    int y = 0;
    if (t >= off) y = ls[t - off];
    __syncthreads();
    x += y;
    ls[t] = x;
    __syncthreads();
  }
  const int excl = x - s;
  #pragma unroll
  for (int j = 0; j < 8; ++j)
    if (base + j < N) out[base + j] = excl + v[j];
  if (t == 255) bsum[blockIdx.x] = x;
}

__global__ __launch_bounds__(64) void scan2_k(const int* __restrict__ bsum,
                                              int* __restrict__ bscan, int NB) {
  const int t = threadIdx.x;
  const int v = (t < NB) ? bsum[t] : 0;
  int x = v;
  #pragma unroll
  for (int off = 1; off < 64; off <<= 1) {
    const int y = __shfl_up(x, off, 64);
    if (t >= off) x += y;
  }
  bscan[t] = x - v;
}

__global__ __launch_bounds__(256) void addoff_k(int* __restrict__ off,
                                                const int* __restrict__ bscan) {
  const int i = blockIdx.x * 256 + threadIdx.x;
  off[i] += bscan[i >> 11];
}

__global__ __launch_bounds__(512) void binscatter_k(const int* __restrict__ src,
                                                    const int* __restrict__ dst,
                                                    const int* __restrict__ histOff,
                                                    unsigned long long* __restrict__ epack,
                                                    int E) {
  __shared__ int cur[256];
  if (threadIdx.x < 256) cur[threadIdx.x] = histOff[threadIdx.x * 256 + blockIdx.x];
  __syncthreads();
  for (int e = blockIdx.x * 512 + threadIdx.x; e < E; e += 256 * 512) {
    const int d = dst[e], s = src[e];
    const int pos = atomicAdd(&cur[d >> 9], 1);
    epack[pos] = ((unsigned long long)(unsigned)d << 32) | (unsigned)s;
  }
}

__global__ __launch_bounds__(512) void binsort_k(const unsigned long long* __restrict__ epack,
                                                 const int* __restrict__ histOff,
                                                 int* __restrict__ rowptr,
                                                 int* __restrict__ col,
                                                 int N, int E) {
  __shared__ int hist[512];
  __shared__ int ls[256];
  __shared__ int cur[512];
  const int b = blockIdx.x;
  const int t = threadIdx.x;
  const int nbins = (N + 511) >> 9;
  const int beg = histOff[b * 256];
  const int end = (b + 1 < nbins) ? histOff[(b + 1) * 256] : E;

  hist[t] = 0;
  __syncthreads();
  for (int j = beg + t; j < end; j += 512)
    atomicAdd(&hist[(int)(epack[j] >> 32) & 511], 1);
  __syncthreads();

  int a = 0, b2 = 0, x = 0;
  if (t < 256) { a = hist[2 * t]; b2 = hist[2 * t + 1]; x = a + b2; ls[t] = x; }
  __syncthreads();
  for (int off = 1; off < 256; off <<= 1) {
    int y = 0;
    if (t < 256 && t >= off) y = ls[t - off];
    __syncthreads();
    if (t < 256) { x += y; ls[t] = x; }
    __syncthreads();
  }
  if (t < 256) {
    const int excl = x - a - b2;
    cur[2 * t] = excl;
    cur[2 * t + 1] = excl + a;
    const int g0 = b * 512 + 2 * t;
    if (g0 <= N) rowptr[g0] = beg + excl;
    if (g0 + 1 <= N) rowptr[g0 + 1] = beg + excl + a;
  }
  __syncthreads();
  for (int j = beg + t; j < end; j += 512) {
    const unsigned long long p = epack[j];
    const int d = (int)(p >> 32) & 511;
    const int s = (int)(p & 0xffffffffu);
    const int pos = atomicAdd(&cur[d], 1);
    col[beg + pos] = s;
  }
}

// ---------------------------------------------------------------------------
// Gather-aggregate, D=128 fp8 rows (128B). Half-wave per edge; lane loads one
// dword (4 fp8 -> 4 f32 via cvt_pk). Cross-half combine via shfl_xor(32).
// ---------------------------------------------------------------------------
__global__ __launch_bounds__(256) void gather128_k(const unsigned* __restrict__ H32,
                                                   const int* __restrict__ rowptr,
                                                   const int* __restrict__ col,
                                                   unsigned* __restrict__ out, int N) {
  const int w = (int)((blockIdx.x * 256u + threadIdx.x) >> 6);
  const int lane = threadIdx.x & 63;
  const int h = lane >> 5;
  const int l5 = lane & 31;
  if (w >= N) return;
  const int beg = __builtin_amdgcn_readfirstlane(rowptr[w]);
  const int end = __builtin_amdgcn_readfirstlane(rowptr[w + 1]);

  float4 acc0 = make_float4(0.f, 0.f, 0.f, 0.f);
  float4 acc1 = make_float4(0.f, 0.f, 0.f, 0.f);
  float4 acc2 = make_float4(0.f, 0.f, 0.f, 0.f);
  float4 acc3 = make_float4(0.f, 0.f, 0.f, 0.f);

  int e = beg;
  for (; e + 8 <= end; e += 8) {
    const int sA = col[e + h];
    const int sB = col[e + 2 + h];
    const int sC = col[e + 4 + h];
    const int sD = col[e + 6 + h];
    const unsigned uA = H32[(size_t)sA * 32 + l5];
    const unsigned uB = H32[(size_t)sB * 32 + l5];
    const unsigned uC = H32[(size_t)sC * 32 + l5];
    const unsigned uD = H32[(size_t)sD * 32 + l5];
    const float4 vA = fp8x4_to_f32(uA), vB = fp8x4_to_f32(uB);
    const float4 vC = fp8x4_to_f32(uC), vD = fp8x4_to_f32(uD);
    acc0.x += vA.x; acc0.y += vA.y; acc0.z += vA.z; acc0.w += vA.w;
    acc1.x += vB.x; acc1.y += vB.y; acc1.z += vB.z; acc1.w += vB.w;
    acc2.x += vC.x; acc2.y += vC.y; acc2.z += vC.z; acc2.w += vC.w;
    acc3.x += vD.x; acc3.y += vD.y; acc3.z += vD.z; acc3.w += vD.w;
  }
  for (; e + 2 <= end; e += 2) {
    const float4 v = fp8x4_to_f32(H32[(size_t)col[e + h] * 32 + l5]);
    acc0.x += v.x; acc0.y += v.y; acc0.z += v.z; acc0.w += v.w;
  }
  if (e < end && h == 0) {
    const float4 v = fp8x4_to_f32(H32[(size_t)col[e] * 32 + l5]);
    acc1.x += v.x; acc1.y += v.y; acc1.z += v.z; acc1.w += v.w;
  }

  float4 a;
  a.x = (acc0.x + acc1.x) + (acc2.x + acc3.x);
  a.y = (acc0.y + acc1.y) + (acc2.y + acc3.y);
  a.z = (acc0.z + acc1.z) + (acc2.z + acc3.z);
  a.w = (acc0.w + acc1.w) + (acc2.w + acc3.w);
  a.x += __shfl_xor(a.x, 32, 64);
  a.y += __shfl_xor(a.y, 32, 64);
  a.z += __shfl_xor(a.z, 32, 64);
  a.w += __shfl_xor(a.w, 32, 64);

  if (h == 0) {
    *reinterpret_cast<uint2*>(&out[(size_t)w * 64 + l5 * 2]) =
        make_uint2(pack_bf16x2(a.x, a.y), pack_bf16x2(a.z, a.w));
  }
}

// ---------------------------------------------------------------------------
// Gather-aggregate D=64 fp8 rows (64B) + fused log_softmax. Quarter-wave per
// edge (4 edges/iter); lane loads one dword (4 fp8). Combine via shfl_xor
// 16/32; softmax reduce within 16-lane groups.
// ---------------------------------------------------------------------------
__global__ __launch_bounds__(256) void gather64lsm_k(const unsigned* __restrict__ H32,
                                                     const int* __restrict__ rowptr,
                                                     const int* __restrict__ col,
                                                     float* __restrict__ out, int N) {
  const int w = (int)((blockIdx.x * 256u + threadIdx.x) >> 6);
  const int lane = threadIdx.x & 63;
  const int q = lane >> 4;                // quarter 0..3
  const int l4 = lane & 15;
  if (w >= N) return;
  const int beg = __builtin_amdgcn_readfirstlane(rowptr[w]);
  const int end = __builtin_amdgcn_readfirstlane(rowptr[w + 1]);

  float4 acc0 = make_float4(0.f, 0.f, 0.f, 0.f);
  float4 acc1 = make_float4(0.f, 0.f, 0.f, 0.f);

  int e = beg;
  for (; e + 8 <= end; e += 8) {
    const int s0 = col[e + q];
    const int s1 = col[e + 4 + q];
    const float4 v0 = fp8x4_to_f32(H32[(size_t)s0 * 16 + l4]);
    const float4 v1 = fp8x4_to_f32(H32[(size_t)s1 * 16 + l4]);
    acc0.x += v0.x; acc0.y += v0.y; acc0.z += v0.z; acc0.w += v0.w;
    acc1.x += v1.x; acc1.y += v1.y; acc1.z += v1.z; acc1.w += v1.w;
  }
  if (e + 4 <= end) {
    const float4 v = fp8x4_to_f32(H32[(size_t)col[e + q] * 16 + l4]);
    acc0.x += v.x; acc0.y += v.y; acc0.z += v.z; acc0.w += v.w;
    e += 4;
  }
  if (e + q < end) {
    const float4 v = fp8x4_to_f32(H32[(size_t)col[e + q] * 16 + l4]);
    acc1.x += v.x; acc1.y += v.y; acc1.z += v.z; acc1.w += v.w;
  }

  float4 a;
  a.x = acc0.x + acc1.x;
  a.y = acc0.y + acc1.y;
  a.z = acc0.z + acc1.z;
  a.w = acc0.w + acc1.w;
  a.x += __shfl_xor(a.x, 16, 64); a.x += __shfl_xor(a.x, 32, 64);
  a.y += __shfl_xor(a.y, 16, 64); a.y += __shfl_xor(a.y, 32, 64);
  a.z += __shfl_xor(a.z, 16, 64); a.z += __shfl_xor(a.z, 32, 64);
  a.w += __shfl_xor(a.w, 16, 64); a.w += __shfl_xor(a.w, 32, 64);

  // all quarters now duplicate; reduce across the 16-lane group.
  float m = fmaxf(fmaxf(a.x, a.y), fmaxf(a.z, a.w));
  #pragma unroll
  for (int o = 8; o > 0; o >>= 1) m = fmaxf(m, __shfl_xor(m, o, 64));
  float s = __expf(a.x - m) + __expf(a.y - m) + __expf(a.z - m) + __expf(a.w - m);
  #pragma unroll
  for (int o = 8; o > 0; o >>= 1) s += __shfl_xor(s, o, 64);
  const float ls = __logf(s);

  if (lane < 16) {
    *reinterpret_cast<float4*>(&out[(size_t)w * 64 + l4 * 4]) =
        make_float4(a.x - m - ls, a.y - m - ls, a.z - m - ls, a.w - m - ls);
  }
}

extern "C" void kernel_launch(void* const* d_in, const int* in_sizes, int n_in,
                              void* d_out, int out_size, void* d_ws, size_t ws_size,
                              hipStream_t stream) {
  const float* x  = (const float*)d_in[0];
  const int*   ei = (const int*)d_in[1];
  const float* W1 = (const float*)d_in[2];
  const float* W2 = (const float*)d_in[3];
  const float* W3 = (const float*)d_in[4];
  float* out = (float*)d_out;

  const int N = in_sizes[0] / KDIM;       // 100000
  const int E = in_sizes[1] / 2;          // 1600000
  const int* src = ei;
  const int* dst = ei + E;

  // Workspace layout (all chunks 16B-aligned)
  unsigned char* H = (unsigned char*)d_ws;              // [N,128] fp8
  unsigned* AGGp = (unsigned*)(H + (size_t)N * 128);    // [N,64] packed bf16 pairs
  unsigned short* Wt1 = (unsigned short*)(AGGp + (size_t)N * 64);  // [128,128]
  unsigned short* Wt2 = Wt1 + 128 * 128;                // [128,128]
  unsigned short* Wt3 = Wt2 + 128 * 128;                // [64,128]
  int* col     = (int*)(Wt3 + 64 * 128);                // [E]
  int* rowptr  = col + E;                               // [N+8]
  int* histT   = rowptr + (N + 8);                      // [65536]
  int* histOff = histT + 65536;                         // [65536]
  int* bsum2   = histOff + 65536;                       // [64]
  int* bscan2  = bsum2 + 64;                            // [64]
  // epack aliases AGGp (dead until layer-1 gather): E*8B <= N*64*4B
  unsigned long long* epack = (unsigned long long*)AGGp;

  const int nbins = (N + 511) / 512;                    // 196

  // ---- W transposes (tiny, once) ----
  wtrans_k<<<(128 * 128 + 255) / 256, 256, 0, stream>>>(W1, Wt1, 128);
  wtrans_k<<<(128 * 128 + 255) / 256, 256, 0, stream>>>(W2, Wt2, 128);
  wtrans_k<<<(64 * 128 + 255) / 256, 256, 0, stream>>>(W3, Wt3, 64);

  // ---- CSR build: bin histogram -> scan -> bin scatter -> per-bin sort ----
  hist_k<<<256, 512, 0, stream>>>(dst, histT, E);
  scan1_k<<<32, 256, 0, stream>>>(histT, histOff, bsum2, 65536);
  scan2_k<<<1, 64, 0, stream>>>(bsum2, bscan2, 32);
  addoff_k<<<256, 256, 0, stream>>>(histOff, bscan2);
  binscatter_k<<<256, 512, 0, stream>>>(src, dst, histOff, epack, E);
  binsort_k<<<nbins, 512, 0, stream>>>(epack, histOff, rowptr, col, N, E);

  const int gemm_grid = (N + 127) / 128;
  const int gather_grid = (N + 3) / 4;

  // ---- layer 1 ----
  gemm_mfma_k<128, true, false><<<gemm_grid, 512, 0, stream>>>(x, Wt1, H, N);
  gather128_k<<<gather_grid, 256, 0, stream>>>((const unsigned*)H, rowptr, col, AGGp, N);

  // ---- layer 2 ----
  gemm_mfma_k<128, false, true><<<gemm_grid, 512, 0, stream>>>(AGGp, Wt2, H, N);
  gather128_k<<<gather_grid, 256, 0, stream>>>((const unsigned*)H, rowptr, col, AGGp, N);

  // ---- layer 3 (+ fused log_softmax) ----
  gemm_mfma_k<64, false, true><<<gemm_grid, 512, 0, stream>>>(AGGp, Wt3, H, N);
  gather64lsm_k<<<gather_grid, 256, 0, stream>>>((const unsigned*)H, rowptr, col, out, N);
}

// Round 9
// 221.651 us; speedup vs baseline: 31.2036x; 1.0499x over previous
//
#include <hip/hip_runtime.h>
#include <hip/hip_bf16.h>

#define KDIM 128

typedef __attribute__((ext_vector_type(8))) __bf16 bf16x8;
typedef __attribute__((ext_vector_type(4))) float f32x4;
typedef __attribute__((ext_vector_type(2))) float f32x2;

// bf16 pack/unpack via explicit bit ops.
static __device__ __forceinline__ unsigned short f2bf(float f) {
  unsigned u = __float_as_uint(f);
  u += 0x7fffu + ((u >> 16) & 1u);        // round-to-nearest-even
  return (unsigned short)(u >> 16);
}
static __device__ __forceinline__ unsigned pack_bf16x2(float a, float b) {
  return (unsigned)f2bf(a) | ((unsigned)f2bf(b) << 16);
}
static __device__ __forceinline__ float2 unpack_bf16x2(unsigned u) {
  return make_float2(__uint_as_float(u << 16), __uint_as_float(u & 0xffff0000u));
}
// ReLU on a packed pair of bf16.
static __device__ __forceinline__ unsigned relu2(unsigned u) {
  unsigned r = u;
  if (u & 0x00008000u) r &= 0xffff0000u;
  if (u & 0x80000000u) r &= 0x0000ffffu;
  return r;
}

// ---------------------------------------------------------------------------
// fp8 (OCP e4m3fn) encode/decode. HW cvt if available, software fallback.
// ---------------------------------------------------------------------------
static __device__ __forceinline__ unsigned char f2fp8(float f) {
#if __has_builtin(__builtin_amdgcn_cvt_pk_fp8_f32)
  return (unsigned char)(__builtin_amdgcn_cvt_pk_fp8_f32(f, f, 0, false) & 0xff);
#else
  unsigned s = (__float_as_uint(f) >> 24) & 0x80u;
  float a = fminf(fabsf(f), 448.f);
  if (a < 0.015625f) {
    unsigned m = (unsigned)(a * 512.f + 0.5f);
    return (unsigned char)(s | m);
  }
  unsigned v = __float_as_uint(a);
  v += 0x7ffffu + ((v >> 20) & 1u);
  unsigned em = (v >> 20) - 960u;
  if (em > 0x7eu) em = 0x7eu;
  return (unsigned char)(s | em);
#endif
}
static __device__ __forceinline__ float fp8dec(unsigned b) {
  unsigned s = (b & 0x80u) << 24;
  unsigned em = b & 0x7fu;
  float mag = (em >= 8) ? __uint_as_float((em + 960u) << 20)
                        : (float)em * 0.001953125f;
  return __uint_as_float(__float_as_uint(mag) | s);
}
static __device__ __forceinline__ float4 fp8x4_to_f32(unsigned u) {
#if __has_builtin(__builtin_amdgcn_cvt_pk_f32_fp8)
  f32x2 lo = __builtin_amdgcn_cvt_pk_f32_fp8(u, false);
  f32x2 hi = __builtin_amdgcn_cvt_pk_f32_fp8(u, true);
  return make_float4(lo[0], lo[1], hi[0], hi[1]);
#else
  return make_float4(fp8dec(u & 255u), fp8dec((u >> 8) & 255u),
                     fp8dec((u >> 16) & 255u), fp8dec(u >> 24));
#endif
}

// ---------------------------------------------------------------------------
// W transpose + bf16 cast: Wt[n][k] = bf16(W[k][n]). K=128 fixed.
// ---------------------------------------------------------------------------
__global__ __launch_bounds__(256) void wtrans_k(const float* __restrict__ W,
                                                unsigned short* __restrict__ Wt,
                                                int NOUT) {
  const int t = blockIdx.x * 256 + threadIdx.x;
  if (t >= NOUT * KDIM) return;
  const int n = t >> 7;
  const int k = t & 127;
  Wt[t] = f2bf(W[k * NOUT + n]);
}

// ---------------------------------------------------------------------------
// MFMA GEMM: C[M,NOUT](fp8) = act(A[M,128]) @ W, W given as Wt[n][k] bf16.
// ---------------------------------------------------------------------------
template<int NOUT, bool AF32, bool RELU>
__global__ __launch_bounds__(512) void gemm_mfma_k(const void* __restrict__ Av,
                                                   const unsigned short* __restrict__ Wt,
                                                   unsigned char* __restrict__ C, int M) {
  constexpr int NT = NOUT / 16;
  __shared__ unsigned short Ws[NOUT][136];

  const int tid = threadIdx.x;
  for (int i = tid; i < NOUT * 16; i += 512) {
    const int n = i >> 4, k8 = i & 15;
    const uint4 v = *reinterpret_cast<const uint4*>(&Wt[n * KDIM + k8 * 8]);
    *reinterpret_cast<uint4*>(&Ws[n][k8 * 8]) = v;
  }

  const int wv = tid >> 6;
  const int l  = tid & 63;
  const int am = l & 15;
  const int kb = l >> 4;
  const int arow_g = blockIdx.x * 128 + wv * 16 + am;
  const bool valid = arow_g < M;
  const int arow = valid ? arow_g : 0;

  uint4 afr[4];
  if constexpr (AF32) {
    const float* A = (const float*)Av;
    #pragma unroll
    for (int ks = 0; ks < 4; ++ks) {
      const float4 lo = *reinterpret_cast<const float4*>(&A[(size_t)arow * 128 + ks * 32 + kb * 8]);
      const float4 hi = *reinterpret_cast<const float4*>(&A[(size_t)arow * 128 + ks * 32 + kb * 8 + 4]);
      afr[ks] = make_uint4(pack_bf16x2(lo.x, lo.y), pack_bf16x2(lo.z, lo.w),
                           pack_bf16x2(hi.x, hi.y), pack_bf16x2(hi.z, hi.w));
    }
  } else {
    const unsigned* A = (const unsigned*)Av;
    #pragma unroll
    for (int ks = 0; ks < 4; ++ks) {
      uint4 u = *reinterpret_cast<const uint4*>(&A[(size_t)arow * 64 + ks * 16 + kb * 4]);
      if constexpr (RELU) {
        u.x = relu2(u.x); u.y = relu2(u.y); u.z = relu2(u.z); u.w = relu2(u.w);
      }
      afr[ks] = u;
    }
  }
  if (!valid) {
    afr[0] = make_uint4(0, 0, 0, 0); afr[1] = afr[0];
    afr[2] = afr[0];                 afr[3] = afr[0];
  }

  f32x4 acc[NT];
  #pragma unroll
  for (int nt = 0; nt < NT; ++nt) {
    acc[nt][0] = 0.f; acc[nt][1] = 0.f; acc[nt][2] = 0.f; acc[nt][3] = 0.f;
  }

  __syncthreads();
  #pragma unroll
  for (int ks = 0; ks < 4; ++ks) {
    const bf16x8 a = __builtin_bit_cast(bf16x8, afr[ks]);
    #pragma unroll
    for (int nt = 0; nt < NT; ++nt) {
      const uint4 bv = *reinterpret_cast<const uint4*>(&Ws[nt * 16 + am][ks * 32 + kb * 8]);
      acc[nt] = __builtin_amdgcn_mfma_f32_16x16x32_bf16(
          a, __builtin_bit_cast(bf16x8, bv), acc[nt], 0, 0, 0);
    }
  }

  const int crow0 = blockIdx.x * 128 + wv * 16 + kb * 4;
  #pragma unroll
  for (int nt = 0; nt < NT; ++nt) {
    #pragma unroll
    for (int r = 0; r < 4; ++r) {
      const int rr = crow0 + r;
      if (rr < M) C[(size_t)rr * NOUT + nt * 16 + am] = f2fp8(acc[nt][r]);
    }
  }
}

// ---------------------------------------------------------------------------
// Bin-grouped CSR build. bin = dst >> 9 (512 nodes/bin, <=256 bins).
// Edge record: u32 = (dst&511)<<17 | src   (src < 2^17).
// ---------------------------------------------------------------------------
__global__ __launch_bounds__(512) void hist_k(const int* __restrict__ dst,
                                              int* __restrict__ histT, int E) {
  __shared__ int h[256];
  if (threadIdx.x < 256) h[threadIdx.x] = 0;
  __syncthreads();
  const int E4 = E >> 2;
  for (int i = blockIdx.x * 512 + threadIdx.x; i < E4; i += 256 * 512) {
    const int4 d4 = *reinterpret_cast<const int4*>(&dst[i * 4]);
    atomicAdd(&h[d4.x >> 9], 1);
    atomicAdd(&h[d4.y >> 9], 1);
    atomicAdd(&h[d4.z >> 9], 1);
    atomicAdd(&h[d4.w >> 9], 1);
  }
  if (blockIdx.x == 0 && threadIdx.x < (E & 3))
    atomicAdd(&h[dst[E4 * 4 + threadIdx.x] >> 9], 1);
  __syncthreads();
  if (threadIdx.x < 256) histT[threadIdx.x * 256 + blockIdx.x] = h[threadIdx.x];
}

__global__ __launch_bounds__(256) void scan1_k(const int* __restrict__ in,
                                               int* __restrict__ out,
                                               int* __restrict__ bsum, int N) {
  __shared__ int ls[256];
  const int t = threadIdx.x;
  const int base = blockIdx.x * 2048 + t * 8;
  int v[8];
  if (base + 8 <= N) {
    *reinterpret_cast<int4*>(&v[0]) = *reinterpret_cast<const int4*>(&in[base]);
    *reinterpret_cast<int4*>(&v[4]) = *reinterpret_cast<const int4*>(&in[base + 4]);
  } else {
    #pragma unroll
    for (int j = 0; j < 8; ++j) v[j] = (base + j < N) ? in[base + j] : 0;
  }
  int s = 0;
  #pragma unroll
  for (int j = 0; j < 8; ++j) { const int tmp = v[j]; v[j] = s; s += tmp; }
  int x = s;
  ls[t] = x;
  __syncthreads();
  for (int off = 1; off < 256; off <<= 1) {
    int y = 0;
    if (t >= off) y = ls[t - off];
    __syncthreads();
    x += y;
    ls[t] = x;
    __syncthreads();
  }
  const int excl = x - s;
  #pragma unroll
  for (int j = 0; j < 8; ++j)
    if (base + j < N) out[base + j] = excl + v[j];
  if (t == 255) bsum[blockIdx.x] = x;
}

__global__ __launch_bounds__(64) void scan2_k(const int* __restrict__ bsum,
                                              int* __restrict__ bscan, int NB) {
  const int t = threadIdx.x;
  const int v = (t < NB) ? bsum[t] : 0;
  int x = v;
  #pragma unroll
  for (int off = 1; off < 64; off <<= 1) {
    const int y = __shfl_up(x, off, 64);
    if (t >= off) x += y;
  }
  bscan[t] = x - v;
}

__global__ __launch_bounds__(256) void addoff_k(int* __restrict__ off,
                                                const int* __restrict__ bscan) {
  const int i = blockIdx.x * 256 + threadIdx.x;
  off[i] += bscan[i >> 11];
}

__global__ __launch_bounds__(512) void binscatter_k(const int* __restrict__ src,
                                                    const int* __restrict__ dst,
                                                    const int* __restrict__ histOff,
                                                    unsigned* __restrict__ epack,
                                                    int E) {
  __shared__ int cur[256];
  if (threadIdx.x < 256) cur[threadIdx.x] = histOff[threadIdx.x * 256 + blockIdx.x];
  __syncthreads();
  const int E4 = E >> 2;
  for (int i = blockIdx.x * 512 + threadIdx.x; i < E4; i += 256 * 512) {
    const int4 d4 = *reinterpret_cast<const int4*>(&dst[i * 4]);
    const int4 s4 = *reinterpret_cast<const int4*>(&src[i * 4]);
    int p;
    p = atomicAdd(&cur[d4.x >> 9], 1); epack[p] = ((unsigned)(d4.x & 511) << 17) | (unsigned)s4.x;
    p = atomicAdd(&cur[d4.y >> 9], 1); epack[p] = ((unsigned)(d4.y & 511) << 17) | (unsigned)s4.y;
    p = atomicAdd(&cur[d4.z >> 9], 1); epack[p] = ((unsigned)(d4.z & 511) << 17) | (unsigned)s4.z;
    p = atomicAdd(&cur[d4.w >> 9], 1); epack[p] = ((unsigned)(d4.w & 511) << 17) | (unsigned)s4.w;
  }
  if (blockIdx.x == 0 && threadIdx.x < (E & 3)) {
    const int e = E4 * 4 + threadIdx.x;
    const int d = dst[e];
    const int p = atomicAdd(&cur[d >> 9], 1);
    epack[p] = ((unsigned)(d & 511) << 17) | (unsigned)src[e];
  }
}

__global__ __launch_bounds__(512) void binsort_k(const unsigned* __restrict__ epack,
                                                 const int* __restrict__ histOff,
                                                 int* __restrict__ rowptr,
                                                 int* __restrict__ col,
                                                 int N, int E) {
  __shared__ int hist[512];
  __shared__ int ls[256];
  __shared__ int cur[512];
  const int b = blockIdx.x;
  const int t = threadIdx.x;
  const int nbins = (N + 511) >> 9;
  const int beg = histOff[b * 256];
  const int end = (b + 1 < nbins) ? histOff[(b + 1) * 256] : E;

  hist[t] = 0;
  __syncthreads();
  for (int j = beg + t; j < end; j += 512)
    atomicAdd(&hist[epack[j] >> 17], 1);
  __syncthreads();

  int a = 0, b2 = 0, x = 0;
  if (t < 256) { a = hist[2 * t]; b2 = hist[2 * t + 1]; x = a + b2; ls[t] = x; }
  __syncthreads();
  for (int off = 1; off < 256; off <<= 1) {
    int y = 0;
    if (t < 256 && t >= off) y = ls[t - off];
    __syncthreads();
    if (t < 256) { x += y; ls[t] = x; }
    __syncthreads();
  }
  if (t < 256) {
    const int excl = x - a - b2;
    cur[2 * t] = excl;
    cur[2 * t + 1] = excl + a;
    const int g0 = b * 512 + 2 * t;
    if (g0 <= N) rowptr[g0] = beg + excl;
    if (g0 + 1 <= N) rowptr[g0 + 1] = beg + excl + a;
  }
  __syncthreads();
  for (int j = beg + t; j < end; j += 512) {
    const unsigned p = epack[j];
    const int pos = atomicAdd(&cur[p >> 17], 1);
    col[beg + pos] = (int)(p & 0x1ffffu);
  }
}

// ---------------------------------------------------------------------------
// Gather-aggregate, D=128 fp8 rows (128B). Half-wave per edge; lane loads one
// dword (4 fp8). 16-edge main loop = 8 independent loads/lane for MLP.
// ---------------------------------------------------------------------------
__global__ __launch_bounds__(256) void gather128_k(const unsigned* __restrict__ H32,
                                                   const int* __restrict__ rowptr,
                                                   const int* __restrict__ col,
                                                   unsigned* __restrict__ out, int N) {
  const int w = (int)((blockIdx.x * 256u + threadIdx.x) >> 6);
  const int lane = threadIdx.x & 63;
  const int h = lane >> 5;
  const int l5 = lane & 31;
  if (w >= N) return;
  const int beg = __builtin_amdgcn_readfirstlane(rowptr[w]);
  const int end = __builtin_amdgcn_readfirstlane(rowptr[w + 1]);

  float4 acc0 = make_float4(0.f, 0.f, 0.f, 0.f);
  float4 acc1 = make_float4(0.f, 0.f, 0.f, 0.f);
  float4 acc2 = make_float4(0.f, 0.f, 0.f, 0.f);
  float4 acc3 = make_float4(0.f, 0.f, 0.f, 0.f);

  int e = beg;
  for (; e + 16 <= end; e += 16) {
    const int s0 = col[e + h];
    const int s1 = col[e + 2 + h];
    const int s2 = col[e + 4 + h];
    const int s3 = col[e + 6 + h];
    const int s4 = col[e + 8 + h];
    const int s5 = col[e + 10 + h];
    const int s6 = col[e + 12 + h];
    const int s7 = col[e + 14 + h];
    const unsigned u0 = H32[(size_t)s0 * 32 + l5];
    const unsigned u1 = H32[(size_t)s1 * 32 + l5];
    const unsigned u2 = H32[(size_t)s2 * 32 + l5];
    const unsigned u3 = H32[(size_t)s3 * 32 + l5];
    const unsigned u4 = H32[(size_t)s4 * 32 + l5];
    const unsigned u5 = H32[(size_t)s5 * 32 + l5];
    const unsigned u6 = H32[(size_t)s6 * 32 + l5];
    const unsigned u7 = H32[(size_t)s7 * 32 + l5];
    float4 v;
    v = fp8x4_to_f32(u0); acc0.x += v.x; acc0.y += v.y; acc0.z += v.z; acc0.w += v.w;
    v = fp8x4_to_f32(u1); acc1.x += v.x; acc1.y += v.y; acc1.z += v.z; acc1.w += v.w;
    v = fp8x4_to_f32(u2); acc2.x += v.x; acc2.y += v.y; acc2.z += v.z; acc2.w += v.w;
    v = fp8x4_to_f32(u3); acc3.x += v.x; acc3.y += v.y; acc3.z += v.z; acc3.w += v.w;
    v = fp8x4_to_f32(u4); acc0.x += v.x; acc0.y += v.y; acc0.z += v.z; acc0.w += v.w;
    v = fp8x4_to_f32(u5); acc1.x += v.x; acc1.y += v.y; acc1.z += v.z; acc1.w += v.w;
    v = fp8x4_to_f32(u6); acc2.x += v.x; acc2.y += v.y; acc2.z += v.z; acc2.w += v.w;
    v = fp8x4_to_f32(u7); acc3.x += v.x; acc3.y += v.y; acc3.z += v.z; acc3.w += v.w;
  }
  for (; e + 8 <= end; e += 8) {
    const int s0 = col[e + h];
    const int s1 = col[e + 2 + h];
    const int s2 = col[e + 4 + h];
    const int s3 = col[e + 6 + h];
    const unsigned u0 = H32[(size_t)s0 * 32 + l5];
    const unsigned u1 = H32[(size_t)s1 * 32 + l5];
    const unsigned u2 = H32[(size_t)s2 * 32 + l5];
    const unsigned u3 = H32[(size_t)s3 * 32 + l5];
    float4 v;
    v = fp8x4_to_f32(u0); acc0.x += v.x; acc0.y += v.y; acc0.z += v.z; acc0.w += v.w;
    v = fp8x4_to_f32(u1); acc1.x += v.x; acc1.y += v.y; acc1.z += v.z; acc1.w += v.w;
    v = fp8x4_to_f32(u2); acc2.x += v.x; acc2.y += v.y; acc2.z += v.z; acc2.w += v.w;
    v = fp8x4_to_f32(u3); acc3.x += v.x; acc3.y += v.y; acc3.z += v.z; acc3.w += v.w;
  }
  for (; e + 2 <= end; e += 2) {
    const float4 v = fp8x4_to_f32(H32[(size_t)col[e + h] * 32 + l5]);
    acc0.x += v.x; acc0.y += v.y; acc0.z += v.z; acc0.w += v.w;
  }
  if (e < end && h == 0) {
    const float4 v = fp8x4_to_f32(H32[(size_t)col[e] * 32 + l5]);
    acc1.x += v.x; acc1.y += v.y; acc1.z += v.z; acc1.w += v.w;
  }

  float4 a;
  a.x = (acc0.x + acc1.x) + (acc2.x + acc3.x);
  a.y = (acc0.y + acc1.y) + (acc2.y + acc3.y);
  a.z = (acc0.z + acc1.z) + (acc2.z + acc3.z);
  a.w = (acc0.w + acc1.w) + (acc2.w + acc3.w);
  a.x += __shfl_xor(a.x, 32, 64);
  a.y += __shfl_xor(a.y, 32, 64);
  a.z += __shfl_xor(a.z, 32, 64);
  a.w += __shfl_xor(a.w, 32, 64);

  if (h == 0) {
    *reinterpret_cast<uint2*>(&out[(size_t)w * 64 + l5 * 2]) =
        make_uint2(pack_bf16x2(a.x, a.y), pack_bf16x2(a.z, a.w));
  }
}

// ---------------------------------------------------------------------------
// Gather-aggregate D=64 fp8 rows (64B) + fused log_softmax. Quarter-wave per
// edge; 16-edge main loop = 4 loads/lane.
// ---------------------------------------------------------------------------
__global__ __launch_bounds__(256) void gather64lsm_k(const unsigned* __restrict__ H32,
                                                     const int* __restrict__ rowptr,
                                                     const int* __restrict__ col,
                                                     float* __restrict__ out, int N) {
  const int w = (int)((blockIdx.x * 256u + threadIdx.x) >> 6);
  const int lane = threadIdx.x & 63;
  const int q = lane >> 4;
  const int l4 = lane & 15;
  if (w >= N) return;
  const int beg = __builtin_amdgcn_readfirstlane(rowptr[w]);
  const int end = __builtin_amdgcn_readfirstlane(rowptr[w + 1]);

  float4 acc0 = make_float4(0.f, 0.f, 0.f, 0.f);
  float4 acc1 = make_float4(0.f, 0.f, 0.f, 0.f);

  int e = beg;
  for (; e + 16 <= end; e += 16) {
    const int s0 = col[e + q];
    const int s1 = col[e + 4 + q];
    const int s2 = col[e + 8 + q];
    const int s3 = col[e + 12 + q];
    const unsigned u0 = H32[(size_t)s0 * 16 + l4];
    const unsigned u1 = H32[(size_t)s1 * 16 + l4];
    const unsigned u2 = H32[(size_t)s2 * 16 + l4];
    const unsigned u3 = H32[(size_t)s3 * 16 + l4];
    float4 v;
    v = fp8x4_to_f32(u0); acc0.x += v.x; acc0.y += v.y; acc0.z += v.z; acc0.w += v.w;
    v = fp8x4_to_f32(u1); acc1.x += v.x; acc1.y += v.y; acc1.z += v.z; acc1.w += v.w;
    v = fp8x4_to_f32(u2); acc0.x += v.x; acc0.y += v.y; acc0.z += v.z; acc0.w += v.w;
    v = fp8x4_to_f32(u3); acc1.x += v.x; acc1.y += v.y; acc1.z += v.z; acc1.w += v.w;
  }
  for (; e + 8 <= end; e += 8) {
    const int s0 = col[e + q];
    const int s1 = col[e + 4 + q];
    const float4 v0 = fp8x4_to_f32(H32[(size_t)s0 * 16 + l4]);
    const float4 v1 = fp8x4_to_f32(H32[(size_t)s1 * 16 + l4]);
    acc0.x += v0.x; acc0.y += v0.y; acc0.z += v0.z; acc0.w += v0.w;
    acc1.x += v1.x; acc1.y += v1.y; acc1.z += v1.z; acc1.w += v1.w;
  }
  if (e + 4 <= end) {
    const float4 v = fp8x4_to_f32(H32[(size_t)col[e + q] * 16 + l4]);
    acc0.x += v.x; acc0.y += v.y; acc0.z += v.z; acc0.w += v.w;
    e += 4;
  }
  if (e + q < end) {
    const float4 v = fp8x4_to_f32(H32[(size_t)col[e + q] * 16 + l4]);
    acc1.x += v.x; acc1.y += v.y; acc1.z += v.z; acc1.w += v.w;
  }

  float4 a;
  a.x = acc0.x + acc1.x;
  a.y = acc0.y + acc1.y;
  a.z = acc0.z + acc1.z;
  a.w = acc0.w + acc1.w;
  a.x += __shfl_xor(a.x, 16, 64); a.x += __shfl_xor(a.x, 32, 64);
  a.y += __shfl_xor(a.y, 16, 64); a.y += __shfl_xor(a.y, 32, 64);
  a.z += __shfl_xor(a.z, 16, 64); a.z += __shfl_xor(a.z, 32, 64);
  a.w += __shfl_xor(a.w, 16, 64); a.w += __shfl_xor(a.w, 32, 64);

  float m = fmaxf(fmaxf(a.x, a.y), fmaxf(a.z, a.w));
  #pragma unroll
  for (int o = 8; o > 0; o >>= 1) m = fmaxf(m, __shfl_xor(m, o, 64));
  float s = __expf(a.x - m) + __expf(a.y - m) + __expf(a.z - m) + __expf(a.w - m);
  #pragma unroll
  for (int o = 8; o > 0; o >>= 1) s += __shfl_xor(s, o, 64);
  const float ls = __logf(s);

  if (lane < 16) {
    *reinterpret_cast<float4*>(&out[(size_t)w * 64 + l4 * 4]) =
        make_float4(a.x - m - ls, a.y - m - ls, a.z - m - ls, a.w - m - ls);
  }
}

extern "C" void kernel_launch(void* const* d_in, const int* in_sizes, int n_in,
                              void* d_out, int out_size, void* d_ws, size_t ws_size,
                              hipStream_t stream) {
  const float* x  = (const float*)d_in[0];
  const int*   ei = (const int*)d_in[1];
  const float* W1 = (const float*)d_in[2];
  const float* W2 = (const float*)d_in[3];
  const float* W3 = (const float*)d_in[4];
  float* out = (float*)d_out;

  const int N = in_sizes[0] / KDIM;       // 100000
  const int E = in_sizes[1] / 2;          // 1600000
  const int* src = ei;
  const int* dst = ei + E;

  // Workspace layout (all chunks 16B-aligned)
  unsigned char* H = (unsigned char*)d_ws;              // [N,128] fp8
  unsigned* AGGp = (unsigned*)(H + (size_t)N * 128);    // [N,64] packed bf16 pairs
  unsigned short* Wt1 = (unsigned short*)(AGGp + (size_t)N * 64);  // [128,128]
  unsigned short* Wt2 = Wt1 + 128 * 128;                // [128,128]
  unsigned short* Wt3 = Wt2 + 128 * 128;                // [64,128]
  int* col     = (int*)(Wt3 + 64 * 128);                // [E]
  int* rowptr  = col + E;                               // [N+8]
  int* histT   = rowptr + (N + 8);                      // [65536]
  int* histOff = histT + 65536;                         // [65536]
  int* bsum2   = histOff + 65536;                       // [64]
  int* bscan2  = bsum2 + 64;                            // [64]
  // epack (u32[E]) aliases AGGp (dead until layer-1 gather): E*4B <= N*64*4B
  unsigned* epack = (unsigned*)AGGp;

  const int nbins = (N + 511) / 512;                    // 196

  // ---- W transposes (tiny, once) ----
  wtrans_k<<<(128 * 128 + 255) / 256, 256, 0, stream>>>(W1, Wt1, 128);
  wtrans_k<<<(128 * 128 + 255) / 256, 256, 0, stream>>>(W2, Wt2, 128);
  wtrans_k<<<(64 * 128 + 255) / 256, 256, 0, stream>>>(W3, Wt3, 64);

  // ---- CSR build: bin histogram -> scan -> bin scatter -> per-bin sort ----
  hist_k<<<256, 512, 0, stream>>>(dst, histT, E);
  scan1_k<<<32, 256, 0, stream>>>(histT, histOff, bsum2, 65536);
  scan2_k<<<1, 64, 0, stream>>>(bsum2, bscan2, 32);
  addoff_k<<<256, 256, 0, stream>>>(histOff, bscan2);
  binscatter_k<<<256, 512, 0, stream>>>(src, dst, histOff, epack, E);
  binsort_k<<<nbins, 512, 0, stream>>>(epack, histOff, rowptr, col, N, E);

  const int gemm_grid = (N + 127) / 128;
  const int gather_grid = (N + 3) / 4;

  // ---- layer 1 ----
  gemm_mfma_k<128, true, false><<<gemm_grid, 512, 0, stream>>>(x, Wt1, H, N);
  gather128_k<<<gather_grid, 256, 0, stream>>>((const unsigned*)H, rowptr, col, AGGp, N);

  // ---- layer 2 ----
  gemm_mfma_k<128, false, true><<<gemm_grid, 512, 0, stream>>>(AGGp, Wt2, H, N);
  gather128_k<<<gather_grid, 256, 0, stream>>>((const unsigned*)H, rowptr, col, AGGp, N);

  // ---- layer 3 (+ fused log_softmax) ----
  gemm_mfma_k<64, false, true><<<gemm_grid, 512, 0, stream>>>(AGGp, Wt3, H, N);
  gather64lsm_k<<<gather_grid, 256, 0, stream>>>((const unsigned*)H, rowptr, col, out, N);
}